// Round 1
// baseline (1326.391 us; speedup 1.0000x reference)
//
#include <hip/hip_runtime.h>
#include <hip/hip_bf16.h>

// ---------------------------------------------------------------------------
// 2-layer GCN: out = A( relu(A(x@W1)+b1) @ W2 ) + b2, A = sym-normalized adj
// with self-loops. All fp32.
// ---------------------------------------------------------------------------

__global__ __launch_bounds__(256) void k_set_deg1(float* deg, int N) {
    int v = blockIdx.x * 256 + threadIdx.x;
    if (v < N) deg[v] = 1.0f;   // self-loop contribution
}

__global__ __launch_bounds__(256) void k_count(const int* __restrict__ col,
                                               float* deg, int E) {
    int e = blockIdx.x * 256 + threadIdx.x;
    if (e < E) atomicAdd(&deg[col[e]], 1.0f);
}

__global__ __launch_bounds__(256) void k_dis(float* deg, int N) {
    int v = blockIdx.x * 256 + threadIdx.x;
    if (v < N) deg[v] = rsqrtf(deg[v]);   // deg >= 1 always
}

// ---------------------------------------------------------------------------
// GEMM1: Hlin[M,128] = X[M,128] @ W[128,128], fp32 vector ALU.
// Tile: 64 rows x 128 cols, BK=32. 256 threads, each computes 4x8.
// ---------------------------------------------------------------------------
__global__ __launch_bounds__(256) void k_gemm1(const float* __restrict__ X,
                                               const float* __restrict__ W,
                                               float* __restrict__ Hlin, int M) {
    __shared__ float Xs[32][65];    // [k][row], pad 65 -> conflict-free
    __shared__ float Ws[32][128];   // [k][col]

    const int tid = threadIdx.x;
    const int tx = tid & 15;        // col group (8 cols each)
    const int ty = tid >> 4;        // row group (4 rows each)
    const int r0 = blockIdx.x * 64;

    float acc[4][8];
#pragma unroll
    for (int i = 0; i < 4; ++i)
#pragma unroll
        for (int j = 0; j < 8; ++j) acc[i][j] = 0.f;

    const int jj = tid & 31;   // k within tile
    const int i0 = tid >> 5;   // 0..7

    for (int kt = 0; kt < 4; ++kt) {
        __syncthreads();
        // stage X transposed: Xs[k][row]
#pragma unroll
        for (int s = 0; s < 8; ++s) {
            int ii = i0 + s * 8;
            int rr = r0 + ii;
            Xs[jj][ii] = (rr < M) ? X[(size_t)rr * 128 + kt * 32 + jj] : 0.f;
        }
        // stage W slice: Ws[k][c]
#pragma unroll
        for (int s = 0; s < 16; ++s) {
            int idx = tid + s * 256;
            int k = idx >> 7, c2 = idx & 127;
            Ws[k][c2] = W[(size_t)(kt * 32 + k) * 128 + c2];
        }
        __syncthreads();

#pragma unroll
        for (int k = 0; k < 32; ++k) {
            float a[4];
#pragma unroll
            for (int i = 0; i < 4; ++i) a[i] = Xs[k][ty * 4 + i];
            float4 b0 = *(const float4*)(&Ws[k][tx * 8]);
            float4 b1v = *(const float4*)(&Ws[k][tx * 8 + 4]);
            float b[8] = {b0.x, b0.y, b0.z, b0.w, b1v.x, b1v.y, b1v.z, b1v.w};
#pragma unroll
            for (int i = 0; i < 4; ++i)
#pragma unroll
                for (int j = 0; j < 8; ++j) acc[i][j] += a[i] * b[j];
        }
    }

#pragma unroll
    for (int i = 0; i < 4; ++i) {
        int rr = r0 + ty * 4 + i;
        if (rr < M) {
            float4 o0 = make_float4(acc[i][0], acc[i][1], acc[i][2], acc[i][3]);
            float4 o1 = make_float4(acc[i][4], acc[i][5], acc[i][6], acc[i][7]);
            *(float4*)(&Hlin[(size_t)rr * 128 + tx * 8]) = o0;
            *(float4*)(&Hlin[(size_t)rr * 128 + tx * 8 + 4]) = o1;
        }
    }
}

// ---------------------------------------------------------------------------
// Layer-1 edge aggregation: agg[col] += hlin[row] * dis[row]*dis[col]
// One thread per (edge, feature). Wave-uniform edge (128 feats, wave=64).
// ---------------------------------------------------------------------------
__global__ __launch_bounds__(256) void k_agg1(const int* __restrict__ row,
                                              const int* __restrict__ col,
                                              const float* __restrict__ dis,
                                              const float* __restrict__ hlin,
                                              float* __restrict__ agg, int E) {
    unsigned long long t = (unsigned long long)blockIdx.x * 256 + threadIdx.x;
    unsigned e = (unsigned)(t >> 7);
    unsigned f = (unsigned)t & 127u;
    if (e >= (unsigned)E) return;
    int r = row[e], c = col[e];
    float w = dis[r] * dis[c];
    atomicAdd(&agg[(size_t)c * 128 + f], hlin[(size_t)r * 128 + f] * w);
}

// h = relu(agg + hlin*dis^2 + b1), in place on agg
__global__ __launch_bounds__(256) void k_relu(float* __restrict__ agg,
                                              const float* __restrict__ hlin,
                                              const float* __restrict__ dis,
                                              const float* __restrict__ b1, int N) {
    int t = blockIdx.x * 256 + threadIdx.x;
    if (t >= N * 128) return;
    int v = t >> 7;
    int f = t & 127;
    float d = dis[v];
    float val = agg[t] + hlin[t] * d * d + b1[f];
    agg[t] = val > 0.f ? val : 0.f;
}

// ---------------------------------------------------------------------------
// GEMM2: Z[M,40] = H[M,128] @ W2[128,40]. One row per thread, W2 in LDS.
// ---------------------------------------------------------------------------
__global__ __launch_bounds__(256) void k_gemm2(const float* __restrict__ Hf,
                                               const float* __restrict__ W2,
                                               float* __restrict__ Z, int M) {
    __shared__ float hs[256][33];
    __shared__ float ws2[128][40];

    const int tid = threadIdx.x;
    const int row0 = blockIdx.x * 256;

    for (int idx = tid; idx < 128 * 40; idx += 256) ((float*)ws2)[idx] = W2[idx];

    float4 acc4[10];
#pragma unroll
    for (int j = 0; j < 10; ++j) acc4[j] = make_float4(0.f, 0.f, 0.f, 0.f);

    const int jj = tid & 31;
    const int i0 = tid >> 5;

    for (int kt = 0; kt < 4; ++kt) {
        __syncthreads();
#pragma unroll
        for (int s = 0; s < 32; ++s) {
            int ii = i0 + s * 8;
            int rr = row0 + ii;
            hs[ii][jj] = (rr < M) ? Hf[(size_t)rr * 128 + kt * 32 + jj] : 0.f;
        }
        __syncthreads();
#pragma unroll
        for (int k = 0; k < 32; ++k) {
            float xv = hs[tid][k];
            const float4* wrow = (const float4*)(&ws2[kt * 32 + k][0]);
#pragma unroll
            for (int j4 = 0; j4 < 10; ++j4) {
                float4 b = wrow[j4];
                acc4[j4].x += xv * b.x;
                acc4[j4].y += xv * b.y;
                acc4[j4].z += xv * b.z;
                acc4[j4].w += xv * b.w;
            }
        }
    }

    int rw = row0 + tid;
    if (rw < M) {
        float4* zp = (float4*)(&Z[(size_t)rw * 40]);
#pragma unroll
        for (int j4 = 0; j4 < 10; ++j4) zp[j4] = acc4[j4];
    }
}

// out[v][j] = b2[j] + z[v][j]*dis[v]^2   (bias + self-loop init)
__global__ __launch_bounds__(256) void k_outinit(float* __restrict__ out,
                                                 const float* __restrict__ z,
                                                 const float* __restrict__ dis,
                                                 const float* __restrict__ b2, int N) {
    unsigned t = blockIdx.x * 256 + threadIdx.x;
    if (t >= (unsigned)(N * 40)) return;
    unsigned v = t / 40u, j = t % 40u;
    float d = dis[v];
    out[t] = b2[j] + z[t] * d * d;
}

// Layer-2 edge aggregation: out[col] += z[row] * dis[row]*dis[col]
__global__ __launch_bounds__(256) void k_agg2(const int* __restrict__ row,
                                              const int* __restrict__ col,
                                              const float* __restrict__ dis,
                                              const float* __restrict__ z,
                                              float* __restrict__ out, int E) {
    unsigned t = blockIdx.x * 256 + threadIdx.x;
    if (t >= (unsigned)E * 40u) return;
    unsigned e = t / 40u, j = t % 40u;
    int r = row[e], c = col[e];
    atomicAdd(&out[(size_t)c * 40 + j], z[(size_t)r * 40 + j] * dis[r] * dis[c]);
}

extern "C" void kernel_launch(void* const* d_in, const int* in_sizes, int n_in,
                              void* d_out, int out_size, void* d_ws, size_t ws_size,
                              hipStream_t stream) {
    const float* x  = (const float*)d_in[0];
    const int*   ei = (const int*)d_in[1];
    const float* W1 = (const float*)d_in[2];
    const float* b1 = (const float*)d_in[3];
    const float* W2 = (const float*)d_in[4];
    const float* b2 = (const float*)d_in[5];
    float* out = (float*)d_out;

    const int N = in_sizes[0] / 128;
    const int E = in_sizes[1] / 2;
    const int* row = ei;       // sources
    const int* col = ei + E;   // targets

    // workspace layout (fp32 elements), ~103 MB total
    float* ws   = (float*)d_ws;
    const int N4 = (N + 3) & ~3;
    float* dis  = ws;                        // N
    float* hlin = ws + N4;                   // N*128
    float* agg1 = hlin + (size_t)N * 128;    // N*128 (becomes h after relu)
    float* z    = hlin;                      // reuse: hlin dead after k_relu

    // degree -> dis
    k_set_deg1<<<(N + 255) / 256, 256, 0, stream>>>(dis, N);
    k_count<<<(E + 255) / 256, 256, 0, stream>>>(col, dis, E);
    k_dis<<<(N + 255) / 256, 256, 0, stream>>>(dis, N);

    // layer 1
    hipMemsetAsync(agg1, 0, (size_t)N * 128 * sizeof(float), stream);
    k_gemm1<<<(N + 63) / 64, 256, 0, stream>>>(x, W1, hlin, N);
    {
        size_t tot = (size_t)E * 128;
        k_agg1<<<(unsigned)((tot + 255) / 256), 256, 0, stream>>>(row, col, dis, hlin, agg1, E);
    }
    k_relu<<<(N * 128 + 255) / 256, 256, 0, stream>>>(agg1, hlin, dis, b1, N);

    // layer 2
    k_gemm2<<<(N + 255) / 256, 256, 0, stream>>>(agg1, W2, z, N);
    k_outinit<<<(N * 40 + 255) / 256, 256, 0, stream>>>(out, z, dis, b2, N);
    {
        size_t tot = (size_t)E * 40;
        k_agg2<<<(unsigned)((tot + 255) / 256), 256, 0, stream>>>(row, col, dis, z, out, E);
    }
}

// Round 3
// 598.527 us; speedup vs baseline: 2.2161x; 2.2161x over previous
//
#include <hip/hip_runtime.h>
#include <hip/hip_bf16.h>

// ---------------------------------------------------------------------------
// 2-layer GCN, atomic-free aggregation via on-device CSC (by target).
// Layer 1 reassociated: h = relu((A x) @ W1 + b1)   [A = normalized adj + self]
// Layer 2:              out = A (h @ W2) + b2
// ---------------------------------------------------------------------------

// ---- degree / norm --------------------------------------------------------
__global__ __launch_bounds__(256) void k_count(const int* __restrict__ col,
                                               int* cnt, int E) {
    int e = blockIdx.x * 256 + threadIdx.x;
    if (e < E) atomicAdd(&cnt[col[e]], 1);
}

__global__ __launch_bounds__(256) void k_dis(const int* __restrict__ cnt,
                                             float* __restrict__ dis, int N) {
    int v = blockIdx.x * 256 + threadIdx.x;
    if (v < N) dis[v] = rsqrtf((float)(cnt[v] + 1));  // +1 self-loop
}

// ---- exclusive scan of cnt -> rowptr (3 kernels) --------------------------
__global__ __launch_bounds__(256) void k_scan_block(const int* __restrict__ cnt,
                                                    int* __restrict__ rowptr,
                                                    int* __restrict__ bsum, int N) {
    __shared__ int s[256];
    int i = blockIdx.x * 256 + threadIdx.x;
    int v = (i < N) ? cnt[i] : 0;
    s[threadIdx.x] = v;
    __syncthreads();
#pragma unroll
    for (int off = 1; off < 256; off <<= 1) {
        int t = (threadIdx.x >= off) ? s[threadIdx.x - off] : 0;
        __syncthreads();
        s[threadIdx.x] += t;
        __syncthreads();
    }
    if (i < N) rowptr[i] = s[threadIdx.x] - v;     // exclusive within block
    if (threadIdx.x == 255) bsum[blockIdx.x] = s[255];
}

__global__ __launch_bounds__(512) void k_scan_bsum(int* bsum, int nb) {
    __shared__ int s[512];
    int t = threadIdx.x;
    int v = (t < nb) ? bsum[t] : 0;
    s[t] = v;
    __syncthreads();
#pragma unroll
    for (int off = 1; off < 512; off <<= 1) {
        int u = (t >= off) ? s[t - off] : 0;
        __syncthreads();
        s[t] += u;
        __syncthreads();
    }
    if (t < nb) bsum[t] = s[t] - v;                // exclusive
}

__global__ __launch_bounds__(256) void k_scan_add(int* __restrict__ rowptr,
                                                  int* __restrict__ cursor,
                                                  const int* __restrict__ bsum,
                                                  int N, int E) {
    int i = blockIdx.x * 256 + threadIdx.x;
    if (i < N) {
        int rp = rowptr[i] + bsum[i >> 8];
        rowptr[i] = rp;
        cursor[i] = rp;
    }
    if (i == 0) rowptr[N] = E;
}

// ---- CSC fill: pair[pos] = {src_row, norm_weight} -------------------------
__global__ __launch_bounds__(256) void k_fill(const int* __restrict__ row,
                                              const int* __restrict__ col,
                                              const float* __restrict__ dis,
                                              int* __restrict__ cursor,
                                              int2* __restrict__ pair, int E) {
    int e = blockIdx.x * 256 + threadIdx.x;
    if (e >= E) return;
    int c = col[e], r = row[e];
    int pos = atomicAdd(&cursor[c], 1);
    pair[pos] = make_int2(r, __float_as_int(dis[r] * dis[c]));
}

// ---- gather layer 1: xa[v] = x[v]*dv^2 + sum x[r]*w  (wave/node, float2) --
__global__ __launch_bounds__(256) void k_gather1(const float* __restrict__ x,
                                                 const int* __restrict__ rowptr,
                                                 const int2* __restrict__ pair,
                                                 const float* __restrict__ dis,
                                                 float* __restrict__ xa, int N) {
    int gw = (blockIdx.x * 256 + threadIdx.x) >> 6;   // node = global wave id
    int lane = threadIdx.x & 63;
    if (gw >= N) return;
    const float2* x2 = (const float2*)x;
    float dv = dis[gw];
    float2 acc = x2[(size_t)gw * 64 + lane];
    float s = dv * dv;
    acc.x *= s; acc.y *= s;
    int j = rowptr[gw], je = rowptr[gw + 1];
    for (; j + 1 < je; j += 2) {
        int2 p0 = pair[j], p1 = pair[j + 1];
        float2 a0 = x2[(size_t)p0.x * 64 + lane];
        float2 a1 = x2[(size_t)p1.x * 64 + lane];
        float w0 = __int_as_float(p0.y), w1 = __int_as_float(p1.y);
        acc.x += a0.x * w0; acc.y += a0.y * w0;
        acc.x += a1.x * w1; acc.y += a1.y * w1;
    }
    if (j < je) {
        int2 p0 = pair[j];
        float2 a0 = x2[(size_t)p0.x * 64 + lane];
        float w0 = __int_as_float(p0.y);
        acc.x += a0.x * w0; acc.y += a0.y * w0;
    }
    ((float2*)xa)[(size_t)gw * 64 + lane] = acc;
}

// ---- GEMM1: H[M,128] = relu(XA[M,128] @ W[128,128] + b1), in-place OK -----
__global__ __launch_bounds__(256) void k_gemm1(const float* X,
                                               const float* __restrict__ W,
                                               const float* __restrict__ bias,
                                               float* H, int M) {
    __shared__ float Xs[32][65];
    __shared__ float Ws[32][128];

    const int tid = threadIdx.x;
    const int tx = tid & 15;
    const int ty = tid >> 4;
    const int r0 = blockIdx.x * 64;

    float acc[4][8];
#pragma unroll
    for (int i = 0; i < 4; ++i)
#pragma unroll
        for (int j = 0; j < 8; ++j) acc[i][j] = 0.f;

    const int jj = tid & 31;
    const int i0 = tid >> 5;

    for (int kt = 0; kt < 4; ++kt) {
        __syncthreads();
#pragma unroll
        for (int s = 0; s < 8; ++s) {
            int ii = i0 + s * 8;
            int rr = r0 + ii;
            Xs[jj][ii] = (rr < M) ? X[(size_t)rr * 128 + kt * 32 + jj] : 0.f;
        }
#pragma unroll
        for (int s = 0; s < 16; ++s) {
            int idx = tid + s * 256;
            int k = idx >> 7, c2 = idx & 127;
            Ws[k][c2] = W[(size_t)(kt * 32 + k) * 128 + c2];
        }
        __syncthreads();

#pragma unroll
        for (int k = 0; k < 32; ++k) {
            float a[4];
#pragma unroll
            for (int i = 0; i < 4; ++i) a[i] = Xs[k][ty * 4 + i];
            float4 b0 = *(const float4*)(&Ws[k][tx * 8]);
            float4 b1v = *(const float4*)(&Ws[k][tx * 8 + 4]);
            float b[8] = {b0.x, b0.y, b0.z, b0.w, b1v.x, b1v.y, b1v.z, b1v.w};
#pragma unroll
            for (int i = 0; i < 4; ++i)
#pragma unroll
                for (int j = 0; j < 8; ++j) acc[i][j] += a[i] * b[j];
        }
    }

    float bb[8];
#pragma unroll
    for (int j = 0; j < 8; ++j) bb[j] = bias[tx * 8 + j];

#pragma unroll
    for (int i = 0; i < 4; ++i) {
        int rr = r0 + ty * 4 + i;
        if (rr < M) {
            float o[8];
#pragma unroll
            for (int j = 0; j < 8; ++j) {
                float v = acc[i][j] + bb[j];
                o[j] = v > 0.f ? v : 0.f;
            }
            *(float4*)(&H[(size_t)rr * 128 + tx * 8])     = make_float4(o[0], o[1], o[2], o[3]);
            *(float4*)(&H[(size_t)rr * 128 + tx * 8 + 4]) = make_float4(o[4], o[5], o[6], o[7]);
        }
    }
}

// ---- GEMM2: Z[M,40] = H[M,128] @ W2[128,40] -------------------------------
__global__ __launch_bounds__(256) void k_gemm2(const float* __restrict__ Hf,
                                               const float* __restrict__ W2,
                                               float* __restrict__ Z, int M) {
    __shared__ float hs[256][33];
    __shared__ float ws2[128][40];

    const int tid = threadIdx.x;
    const int row0 = blockIdx.x * 256;

    for (int idx = tid; idx < 128 * 40; idx += 256) ((float*)ws2)[idx] = W2[idx];

    float4 acc4[10];
#pragma unroll
    for (int j = 0; j < 10; ++j) acc4[j] = make_float4(0.f, 0.f, 0.f, 0.f);

    const int jj = tid & 31;
    const int i0 = tid >> 5;

    for (int kt = 0; kt < 4; ++kt) {
        __syncthreads();
#pragma unroll
        for (int s = 0; s < 32; ++s) {
            int ii = i0 + s * 8;
            int rr = row0 + ii;
            hs[ii][jj] = (rr < M) ? Hf[(size_t)rr * 128 + kt * 32 + jj] : 0.f;
        }
        __syncthreads();
#pragma unroll
        for (int k = 0; k < 32; ++k) {
            float xv = hs[tid][k];
            const float4* wrow = (const float4*)(&ws2[kt * 32 + k][0]);
#pragma unroll
            for (int j4 = 0; j4 < 10; ++j4) {
                float4 b = wrow[j4];
                acc4[j4].x += xv * b.x;
                acc4[j4].y += xv * b.y;
                acc4[j4].z += xv * b.z;
                acc4[j4].w += xv * b.w;
            }
        }
    }

    int rw = row0 + tid;
    if (rw < M) {
        float4* zp = (float4*)(&Z[(size_t)rw * 40]);
#pragma unroll
        for (int j4 = 0; j4 < 10; ++j4) zp[j4] = acc4[j4];
    }
}

// ---- gather layer 2: out[v] = b2 + z[v]*dv^2 + sum z[r]*w  (wave/node) ----
__global__ __launch_bounds__(256) void k_gather2(const float* __restrict__ z,
                                                 const int* __restrict__ rowptr,
                                                 const int2* __restrict__ pair,
                                                 const float* __restrict__ dis,
                                                 const float* __restrict__ b2,
                                                 float* __restrict__ out, int N) {
    int gw = (blockIdx.x * 256 + threadIdx.x) >> 6;
    int lane = threadIdx.x & 63;
    if (gw >= N) return;
    int f = lane < 40 ? lane : 39;   // clamp: lanes 40..63 compute garbage, don't store
    float dv = dis[gw];
    float acc = z[(size_t)gw * 40 + f] * dv * dv + b2[f];
    int j = rowptr[gw], je = rowptr[gw + 1];
    for (; j + 1 < je; j += 2) {
        int2 p0 = pair[j], p1 = pair[j + 1];
        float z0 = z[(size_t)p0.x * 40 + f];
        float z1 = z[(size_t)p1.x * 40 + f];
        acc += z0 * __int_as_float(p0.y);
        acc += z1 * __int_as_float(p1.y);
    }
    if (j < je) {
        int2 p0 = pair[j];
        acc += z[(size_t)p0.x * 40 + f] * __int_as_float(p0.y);
    }
    if (lane < 40) out[(size_t)gw * 40 + lane] = acc;
}

// ---------------------------------------------------------------------------
extern "C" void kernel_launch(void* const* d_in, const int* in_sizes, int n_in,
                              void* d_out, int out_size, void* d_ws, size_t ws_size,
                              hipStream_t stream) {
    const float* x  = (const float*)d_in[0];
    const int*   ei = (const int*)d_in[1];
    const float* W1 = (const float*)d_in[2];
    const float* b1 = (const float*)d_in[3];
    const float* W2 = (const float*)d_in[4];
    const float* b2 = (const float*)d_in[5];
    float* out = (float*)d_out;

    const int N = in_sizes[0] / 128;
    const int E = in_sizes[1] / 2;
    const int* row = ei;        // sources
    const int* col = ei + E;    // targets

    const int Np = (N + 255) & ~255;   // padded element counts for alignment
    const int nb = (N + 255) / 256;    // scan blocks (must be <= 512)

    // workspace layout (4-byte elements), ~82 MB total
    int*   base_i = (int*)d_ws;
    int*   cnt    = base_i;                    // Np
    int*   rowptr = cnt + Np;                  // Np + 256 (need N+1)
    int*   cursor = rowptr + Np + 256;         // Np
    int*   bsum   = cursor + Np;               // 1024
    float* dis    = (float*)(bsum + 1024);     // Np
    int2*  pair   = (int2*)(dis + Np);         // E int2
    float* xa     = (float*)(pair + E);        // N*128  (becomes h in-place)
    float* z      = xa + (size_t)N * 128;      // N*40

    // degree / norm
    hipMemsetAsync(cnt, 0, (size_t)Np * sizeof(int), stream);
    k_count<<<(E + 255) / 256, 256, 0, stream>>>(col, cnt, E);
    k_dis<<<(N + 255) / 256, 256, 0, stream>>>(cnt, dis, N);

    // CSC build
    k_scan_block<<<nb, 256, 0, stream>>>(cnt, rowptr, bsum, N);
    k_scan_bsum<<<1, 512, 0, stream>>>(bsum, nb);
    k_scan_add<<<nb, 256, 0, stream>>>(rowptr, cursor, bsum, N, E);
    k_fill<<<(E + 255) / 256, 256, 0, stream>>>(row, col, dis, cursor, pair, E);

    // layer 1: xa = A x ; h = relu(xa @ W1 + b1) in-place
    k_gather1<<<(N + 3) / 4, 256, 0, stream>>>(x, rowptr, pair, dis, xa, N);
    k_gemm1<<<(N + 63) / 64, 256, 0, stream>>>(xa, W1, b1, xa, N);

    // layer 2: z = h @ W2 ; out = b2 + A z
    k_gemm2<<<(N + 255) / 256, 256, 0, stream>>>(xa, W2, z, N);
    k_gather2<<<(N + 3) / 4, 256, 0, stream>>>(z, rowptr, pair, dis, b2, out, N);
}

// Round 4
// 520.418 us; speedup vs baseline: 2.5487x; 1.1501x over previous
//
#include <hip/hip_runtime.h>
#include <hip/hip_bf16.h>

// ---------------------------------------------------------------------------
// 2-layer GCN, atomic-free CSC gather aggregation, bf16 gather payloads.
// Layer 1: h = relu((A x) @ W1 + b1)   [reassociated; A = norm adj + self]
// Layer 2: out = A (h @ W2) + b2
// Gathers read bf16-packed rows (halved traffic), accumulate fp32.
// ---------------------------------------------------------------------------

__device__ __forceinline__ unsigned bf16rn(float f) {
    unsigned x = __float_as_uint(f);
    unsigned r = ((x >> 16) & 1u) + 0x7fffu;   // RNE
    return (x + r) >> 16;
}
__device__ __forceinline__ float bf_lo(unsigned u) { return __uint_as_float(u << 16); }
__device__ __forceinline__ float bf_hi(unsigned u) { return __uint_as_float(u & 0xffff0000u); }

// ---- degree count ---------------------------------------------------------
__global__ __launch_bounds__(256) void k_count(const int* __restrict__ col,
                                               int* cnt, int E) {
    int e = blockIdx.x * 256 + threadIdx.x;
    if (e < E) atomicAdd(&cnt[col[e]], 1);
}

// ---- block scan of cnt -> rowptr(excl within block) + bsum + dis ----------
__global__ __launch_bounds__(256) void k_scan_block(const int* __restrict__ cnt,
                                                    int* __restrict__ rowptr,
                                                    int* __restrict__ bsum,
                                                    float* __restrict__ dis, int N) {
    __shared__ int s[256];
    int i = blockIdx.x * 256 + threadIdx.x;
    int v = (i < N) ? cnt[i] : 0;
    if (i < N) dis[i] = rsqrtf((float)(v + 1));   // +1 self-loop
    s[threadIdx.x] = v;
    __syncthreads();
#pragma unroll
    for (int off = 1; off < 256; off <<= 1) {
        int t = (threadIdx.x >= off) ? s[threadIdx.x - off] : 0;
        __syncthreads();
        s[threadIdx.x] += t;
        __syncthreads();
    }
    if (i < N) rowptr[i] = s[threadIdx.x] - v;
    if (threadIdx.x == 255) bsum[blockIdx.x] = s[255];
}

__global__ __launch_bounds__(512) void k_scan_bsum(int* bsum, int nb) {
    __shared__ int s[512];
    int t = threadIdx.x;
    int v = (t < nb) ? bsum[t] : 0;
    s[t] = v;
    __syncthreads();
#pragma unroll
    for (int off = 1; off < 512; off <<= 1) {
        int u = (t >= off) ? s[t - off] : 0;
        __syncthreads();
        s[t] += u;
        __syncthreads();
    }
    if (t < nb) bsum[t] = s[t] - v;
}

__global__ __launch_bounds__(256) void k_scan_add(int* __restrict__ rowptr,
                                                  int* __restrict__ cursor,
                                                  const int* __restrict__ bsum,
                                                  int N, int E) {
    int i = blockIdx.x * 256 + threadIdx.x;
    if (i < N) {
        int rp = rowptr[i] + bsum[i >> 8];
        rowptr[i] = rp;
        cursor[i] = rp;
    }
    if (i == 0) rowptr[N] = E;
}

// ---- CSC fill: pair[pos] = {src_row, norm_weight} -------------------------
__global__ __launch_bounds__(256) void k_fill(const int* __restrict__ row,
                                              const int* __restrict__ col,
                                              const float* __restrict__ dis,
                                              int* __restrict__ cursor,
                                              int2* __restrict__ pair, int E) {
    int e = blockIdx.x * 256 + threadIdx.x;
    if (e >= E) return;
    int c = col[e], r = row[e];
    int pos = atomicAdd(&cursor[c], 1);
    pair[pos] = make_int2(r, __float_as_int(dis[r] * dis[c]));
}

// ---- convert x (fp32) -> xb (bf16x2 packed, 64 uints/row) -----------------
__global__ __launch_bounds__(256) void k_cvt(const float* __restrict__ x,
                                             unsigned* __restrict__ xb, int n64) {
    int i = blockIdx.x * 256 + threadIdx.x;
    if (i >= n64) return;
    float2 v = ((const float2*)x)[i];
    xb[i] = bf16rn(v.x) | (bf16rn(v.y) << 16);
}

// ---- gather layer 1: xa[v] = x[v]*dv^2 + sum x[r]*w  (wave/node) ----------
// xb rows: 64 uints (128 bf16). lane handles feats {2*lane, 2*lane+1}.
__global__ __launch_bounds__(256) void k_gather1(const unsigned* __restrict__ xb,
                                                 const int* __restrict__ rowptr,
                                                 const int2* __restrict__ pair,
                                                 const float* __restrict__ dis,
                                                 float* __restrict__ xa, int N) {
    int gw = (blockIdx.x * 256 + threadIdx.x) >> 6;
    int lane = threadIdx.x & 63;
    if (gw >= N) return;
    float dv = dis[gw];
    unsigned us = xb[(size_t)gw * 64 + lane];
    float s = dv * dv;
    float2 acc = make_float2(bf_lo(us) * s, bf_hi(us) * s);
    int j = rowptr[gw], je = rowptr[gw + 1];
    for (; j + 3 < je; j += 4) {
        int2 p0 = pair[j], p1 = pair[j + 1], p2 = pair[j + 2], p3 = pair[j + 3];
        unsigned a0 = xb[(size_t)p0.x * 64 + lane];
        unsigned a1 = xb[(size_t)p1.x * 64 + lane];
        unsigned a2 = xb[(size_t)p2.x * 64 + lane];
        unsigned a3 = xb[(size_t)p3.x * 64 + lane];
        float w0 = __int_as_float(p0.y), w1 = __int_as_float(p1.y);
        float w2 = __int_as_float(p2.y), w3 = __int_as_float(p3.y);
        acc.x += bf_lo(a0) * w0; acc.y += bf_hi(a0) * w0;
        acc.x += bf_lo(a1) * w1; acc.y += bf_hi(a1) * w1;
        acc.x += bf_lo(a2) * w2; acc.y += bf_hi(a2) * w2;
        acc.x += bf_lo(a3) * w3; acc.y += bf_hi(a3) * w3;
    }
    for (; j < je; ++j) {
        int2 p0 = pair[j];
        unsigned a0 = xb[(size_t)p0.x * 64 + lane];
        float w0 = __int_as_float(p0.y);
        acc.x += bf_lo(a0) * w0; acc.y += bf_hi(a0) * w0;
    }
    ((float2*)xa)[(size_t)gw * 64 + lane] = acc;
}

// ---- GEMM1: H[M,128] = relu(XA[M,128] @ W[128,128] + b1), in-place OK -----
__global__ __launch_bounds__(256) void k_gemm1(const float* X,
                                               const float* __restrict__ W,
                                               const float* __restrict__ bias,
                                               float* H, int M) {
    __shared__ float Xs[32][65];
    __shared__ float Ws[32][128];

    const int tid = threadIdx.x;
    const int tx = tid & 15;
    const int ty = tid >> 4;
    const int r0 = blockIdx.x * 64;

    float acc[4][8];
#pragma unroll
    for (int i = 0; i < 4; ++i)
#pragma unroll
        for (int j = 0; j < 8; ++j) acc[i][j] = 0.f;

    const int jj = tid & 31;
    const int i0 = tid >> 5;

    for (int kt = 0; kt < 4; ++kt) {
        __syncthreads();
#pragma unroll
        for (int s = 0; s < 8; ++s) {
            int ii = i0 + s * 8;
            int rr = r0 + ii;
            Xs[jj][ii] = (rr < M) ? X[(size_t)rr * 128 + kt * 32 + jj] : 0.f;
        }
#pragma unroll
        for (int s = 0; s < 16; ++s) {
            int idx = tid + s * 256;
            int k = idx >> 7, c2 = idx & 127;
            Ws[k][c2] = W[(size_t)(kt * 32 + k) * 128 + c2];
        }
        __syncthreads();

#pragma unroll
        for (int k = 0; k < 32; ++k) {
            float a[4];
#pragma unroll
            for (int i = 0; i < 4; ++i) a[i] = Xs[k][ty * 4 + i];
            float4 b0 = *(const float4*)(&Ws[k][tx * 8]);
            float4 b1v = *(const float4*)(&Ws[k][tx * 8 + 4]);
            float b[8] = {b0.x, b0.y, b0.z, b0.w, b1v.x, b1v.y, b1v.z, b1v.w};
#pragma unroll
            for (int i = 0; i < 4; ++i)
#pragma unroll
                for (int j = 0; j < 8; ++j) acc[i][j] += a[i] * b[j];
        }
    }

    float bb[8];
#pragma unroll
    for (int j = 0; j < 8; ++j) bb[j] = bias[tx * 8 + j];

#pragma unroll
    for (int i = 0; i < 4; ++i) {
        int rr = r0 + ty * 4 + i;
        if (rr < M) {
            float o[8];
#pragma unroll
            for (int j = 0; j < 8; ++j) {
                float v = acc[i][j] + bb[j];
                o[j] = v > 0.f ? v : 0.f;
            }
            *(float4*)(&H[(size_t)rr * 128 + tx * 8])     = make_float4(o[0], o[1], o[2], o[3]);
            *(float4*)(&H[(size_t)rr * 128 + tx * 8 + 4]) = make_float4(o[4], o[5], o[6], o[7]);
        }
    }
}

// ---- GEMM2: Zb[M,40](bf16) = H[M,128] @ W2[128,40] ------------------------
__global__ __launch_bounds__(256) void k_gemm2(const float* __restrict__ Hf,
                                               const float* __restrict__ W2,
                                               unsigned* __restrict__ Zb, int M) {
    __shared__ float hs[256][33];
    __shared__ float ws2[128][40];

    const int tid = threadIdx.x;
    const int row0 = blockIdx.x * 256;

    for (int idx = tid; idx < 128 * 40; idx += 256) ((float*)ws2)[idx] = W2[idx];

    float4 acc4[10];
#pragma unroll
    for (int j = 0; j < 10; ++j) acc4[j] = make_float4(0.f, 0.f, 0.f, 0.f);

    const int jj = tid & 31;
    const int i0 = tid >> 5;

    for (int kt = 0; kt < 4; ++kt) {
        __syncthreads();
#pragma unroll
        for (int s = 0; s < 32; ++s) {
            int ii = i0 + s * 8;
            int rr = row0 + ii;
            hs[ii][jj] = (rr < M) ? Hf[(size_t)rr * 128 + kt * 32 + jj] : 0.f;
        }
        __syncthreads();
#pragma unroll
        for (int k = 0; k < 32; ++k) {
            float xv = hs[tid][k];
            const float4* wrow = (const float4*)(&ws2[kt * 32 + k][0]);
#pragma unroll
            for (int j4 = 0; j4 < 10; ++j4) {
                float4 b = wrow[j4];
                acc4[j4].x += xv * b.x;
                acc4[j4].y += xv * b.y;
                acc4[j4].z += xv * b.z;
                acc4[j4].w += xv * b.w;
            }
        }
    }

    int rw = row0 + tid;
    if (rw < M) {
        unsigned pk[20];
#pragma unroll
        for (int j4 = 0; j4 < 10; ++j4) {
            pk[j4 * 2]     = bf16rn(acc4[j4].x) | (bf16rn(acc4[j4].y) << 16);
            pk[j4 * 2 + 1] = bf16rn(acc4[j4].z) | (bf16rn(acc4[j4].w) << 16);
        }
        uint4* zp = (uint4*)(&Zb[(size_t)rw * 20]);
#pragma unroll
        for (int q = 0; q < 5; ++q)
            zp[q] = make_uint4(pk[q * 4], pk[q * 4 + 1], pk[q * 4 + 2], pk[q * 4 + 3]);
    }
}

// ---- gather layer 2: out[v] = b2 + z[v]*dv^2 + sum z[r]*w -----------------
// zb rows: 20 uints (40 bf16). Wave per node; half-waves each take one edge
// per iteration (lanes 0..19 / 32..51 active, 2 feats per lane).
__global__ __launch_bounds__(256) void k_gather2(const unsigned* __restrict__ zb,
                                                 const int* __restrict__ rowptr,
                                                 const int2* __restrict__ pair,
                                                 const float* __restrict__ dis,
                                                 const float* __restrict__ b2,
                                                 float* __restrict__ out, int N) {
    int gw = (blockIdx.x * 256 + threadIdx.x) >> 6;
    int lane = threadIdx.x & 63;
    if (gw >= N) return;
    int sub = lane >> 5;        // 0: lower half-wave, 1: upper
    int sl  = lane & 31;
    int f   = (sl < 20) ? sl : 19;   // clamped feat-pair index

    float2 acc = make_float2(0.f, 0.f);
    float dv = dis[gw];
    if (sub == 0) {
        unsigned u = zb[(size_t)gw * 20 + f];
        float s = dv * dv;
        acc.x = bf_lo(u) * s; acc.y = bf_hi(u) * s;
    }

    int j = rowptr[gw], je = rowptr[gw + 1];
    for (; j + 3 < je; j += 4) {
        int2 pA = pair[j + sub];
        int2 pB = pair[j + 2 + sub];
        unsigned uA = zb[(size_t)pA.x * 20 + f];
        unsigned uB = zb[(size_t)pB.x * 20 + f];
        float wA = __int_as_float(pA.y), wB = __int_as_float(pB.y);
        acc.x += bf_lo(uA) * wA; acc.y += bf_hi(uA) * wA;
        acc.x += bf_lo(uB) * wB; acc.y += bf_hi(uB) * wB;
    }
    for (; j + 1 < je; j += 2) {
        int2 p = pair[j + sub];
        unsigned u = zb[(size_t)p.x * 20 + f];
        float w = __int_as_float(p.y);
        acc.x += bf_lo(u) * w; acc.y += bf_hi(u) * w;
    }
    if (j < je && sub == 0) {
        int2 p = pair[j];
        unsigned u = zb[(size_t)p.x * 20 + f];
        float w = __int_as_float(p.y);
        acc.x += bf_lo(u) * w; acc.y += bf_hi(u) * w;
    }

    // combine the two half-wave partial sums into the lower half
    float bx = __shfl(acc.x, sl + 32, 64);
    float by = __shfl(acc.y, sl + 32, 64);
    if (sub == 0 && sl < 20) {
        float2 bias = ((const float2*)b2)[sl];
        float2 res = make_float2(acc.x + bx + bias.x, acc.y + by + bias.y);
        ((float2*)(out + (size_t)gw * 40))[sl] = res;
    }
}

// ---------------------------------------------------------------------------
extern "C" void kernel_launch(void* const* d_in, const int* in_sizes, int n_in,
                              void* d_out, int out_size, void* d_ws, size_t ws_size,
                              hipStream_t stream) {
    const float* x  = (const float*)d_in[0];
    const int*   ei = (const int*)d_in[1];
    const float* W1 = (const float*)d_in[2];
    const float* b1 = (const float*)d_in[3];
    const float* W2 = (const float*)d_in[4];
    const float* b2 = (const float*)d_in[5];
    float* out = (float*)d_out;

    const int N = in_sizes[0] / 128;
    const int E = in_sizes[1] / 2;
    const int* row = ei;        // sources
    const int* col = ei + E;    // targets

    const int Np = (N + 255) & ~255;
    const int nb = (N + 255) / 256;    // must be <= 512

    // workspace layout (4-byte units), ~99 MB total
    int*      cnt    = (int*)d_ws;                 // Np
    int*      rowptr = cnt + Np;                   // Np + 256
    int*      cursor = rowptr + Np + 256;          // Np
    int*      bsum   = cursor + Np;                // 1024
    float*    dis    = (float*)(bsum + 1024);      // Np
    int2*     pair   = (int2*)(dis + Np);          // E int2
    unsigned* xb     = (unsigned*)(pair + E);      // N*64 uints (bf16 x)
    float*    xa     = (float*)(xb + (size_t)N * 64);  // N*128 f32 (becomes h)
    unsigned* zb     = (unsigned*)(xa + (size_t)N * 128); // N*20 uints (bf16 z)

    // degree / norm / CSC build
    hipMemsetAsync(cnt, 0, (size_t)Np * sizeof(int), stream);
    k_count<<<(E + 255) / 256, 256, 0, stream>>>(col, cnt, E);
    k_scan_block<<<nb, 256, 0, stream>>>(cnt, rowptr, bsum, dis, N);
    k_scan_bsum<<<1, 512, 0, stream>>>(bsum, nb);
    k_scan_add<<<nb, 256, 0, stream>>>(rowptr, cursor, bsum, N, E);
    k_fill<<<(E + 255) / 256, 256, 0, stream>>>(row, col, dis, cursor, pair, E);

    // x -> bf16
    k_cvt<<<(N * 64 + 255) / 256, 256, 0, stream>>>(x, xb, N * 64);

    // layer 1: xa = A x ; h = relu(xa @ W1 + b1) in-place
    k_gather1<<<(N + 3) / 4, 256, 0, stream>>>(xb, rowptr, pair, dis, xa, N);
    k_gemm1<<<(N + 63) / 64, 256, 0, stream>>>(xa, W1, b1, xa, N);

    // layer 2: zb = bf16(h @ W2) ; out = b2 + A z
    k_gemm2<<<(N + 255) / 256, 256, 0, stream>>>(xa, W2, zb, N);
    k_gather2<<<(N + 3) / 4, 256, 0, stream>>>(zb, rowptr, pair, dis, b2, out, N);
}

// Round 5
// 455.227 us; speedup vs baseline: 2.9137x; 1.1432x over previous
//
#include <hip/hip_runtime.h>
#include <hip/hip_bf16.h>

// ---------------------------------------------------------------------------
// 2-layer GCN, atomic-free CSC gather, bf16 payloads + bf16 MFMA GEMM1.
// Layer 1: h = relu((A x) @ W1 + b1)   [reassociated; A = norm adj + self]
// Layer 2: out = A (h @ W2) + b2
// ---------------------------------------------------------------------------

__device__ __forceinline__ unsigned bf16rn(float f) {
    unsigned x = __float_as_uint(f);
    unsigned r = ((x >> 16) & 1u) + 0x7fffu;   // RNE
    return (x + r) >> 16;
}
__device__ __forceinline__ float bf_lo(unsigned u) { return __uint_as_float(u << 16); }
__device__ __forceinline__ float bf_hi(unsigned u) { return __uint_as_float(u & 0xffff0000u); }

typedef __bf16 bf16x8 __attribute__((ext_vector_type(8)));
typedef float  f32x4  __attribute__((ext_vector_type(4)));

// ---- degree count ---------------------------------------------------------
__global__ __launch_bounds__(256) void k_count(const int* __restrict__ col,
                                               int* cnt, int E) {
    int e = blockIdx.x * 256 + threadIdx.x;
    if (e < E) atomicAdd(&cnt[col[e]], 1);
}

// ---- block scan of cnt -> rowptr(excl within block) + bsum + dis ----------
__global__ __launch_bounds__(256) void k_scan_block(const int* __restrict__ cnt,
                                                    int* __restrict__ rowptr,
                                                    int* __restrict__ bsum,
                                                    float* __restrict__ dis, int N) {
    __shared__ int s[256];
    int i = blockIdx.x * 256 + threadIdx.x;
    int v = (i < N) ? cnt[i] : 0;
    if (i < N) dis[i] = rsqrtf((float)(v + 1));   // +1 self-loop
    s[threadIdx.x] = v;
    __syncthreads();
#pragma unroll
    for (int off = 1; off < 256; off <<= 1) {
        int t = (threadIdx.x >= off) ? s[threadIdx.x - off] : 0;
        __syncthreads();
        s[threadIdx.x] += t;
        __syncthreads();
    }
    if (i < N) rowptr[i] = s[threadIdx.x] - v;
    if (threadIdx.x == 255) bsum[blockIdx.x] = s[255];
}

__global__ __launch_bounds__(512) void k_scan_bsum(int* bsum, int nb) {
    __shared__ int s[512];
    int t = threadIdx.x;
    int v = (t < nb) ? bsum[t] : 0;
    s[t] = v;
    __syncthreads();
#pragma unroll
    for (int off = 1; off < 512; off <<= 1) {
        int u = (t >= off) ? s[t - off] : 0;
        __syncthreads();
        s[t] += u;
        __syncthreads();
    }
    if (t < nb) bsum[t] = s[t] - v;
}

__global__ __launch_bounds__(256) void k_scan_add(int* __restrict__ rowptr,
                                                  int* __restrict__ cursor,
                                                  const int* __restrict__ bsum,
                                                  int N, int E) {
    int i = blockIdx.x * 256 + threadIdx.x;
    if (i < N) {
        int rp = rowptr[i] + bsum[i >> 8];
        rowptr[i] = rp;
        cursor[i] = rp;
    }
    if (i == 0) rowptr[N] = E;
}

// ---- CSC fill: pair[pos] = {src_row, norm_weight} -------------------------
__global__ __launch_bounds__(256) void k_fill(const int* __restrict__ row,
                                              const int* __restrict__ col,
                                              const float* __restrict__ dis,
                                              int* __restrict__ cursor,
                                              int2* __restrict__ pair, int E) {
    int e = blockIdx.x * 256 + threadIdx.x;
    if (e >= E) return;
    int c = col[e], r = row[e];
    int pos = atomicAdd(&cursor[c], 1);
    pair[pos] = make_int2(r, __float_as_int(dis[r] * dis[c]));
}

// ---- convert x (fp32) -> xb (bf16x2 packed, 64 uints/row) -----------------
__global__ __launch_bounds__(256) void k_cvt(const float* __restrict__ x,
                                             unsigned* __restrict__ xb, int n64) {
    int i = blockIdx.x * 256 + threadIdx.x;
    if (i >= n64) return;
    float2 v = ((const float2*)x)[i];
    xb[i] = bf16rn(v.x) | (bf16rn(v.y) << 16);
}

// ---- W1 [128k][128n] fp32 -> W1t [n][k] bf16x2-packed (64 uints/row) ------
__global__ __launch_bounds__(256) void k_cvtW(const float* __restrict__ W1,
                                              unsigned* __restrict__ Wt) {
    int t = blockIdx.x * 256 + threadIdx.x;   // 8192 uints
    if (t >= 8192) return;
    int n = t >> 6, kk = (t & 63) * 2;
    unsigned lo = bf16rn(W1[(size_t)kk * 128 + n]);
    unsigned hi = bf16rn(W1[(size_t)(kk + 1) * 128 + n]);
    Wt[t] = lo | (hi << 16);
}

// ---- gather layer 1: xab[v] = bf16(x[v]*dv^2 + sum x[r]*w)  (wave/node) ---
__global__ __launch_bounds__(256) void k_gather1(const unsigned* __restrict__ xb,
                                                 const int* __restrict__ rowptr,
                                                 const int2* __restrict__ pair,
                                                 const float* __restrict__ dis,
                                                 unsigned* __restrict__ xab, int N) {
    int gw = (blockIdx.x * 256 + threadIdx.x) >> 6;
    int lane = threadIdx.x & 63;
    if (gw >= N) return;
    float dv = dis[gw];
    unsigned us = xb[(size_t)gw * 64 + lane];
    float s = dv * dv;
    float2 acc = make_float2(bf_lo(us) * s, bf_hi(us) * s);
    int j = rowptr[gw], je = rowptr[gw + 1];
    for (; j + 3 < je; j += 4) {
        int2 p0 = pair[j], p1 = pair[j + 1], p2 = pair[j + 2], p3 = pair[j + 3];
        unsigned a0 = xb[(size_t)p0.x * 64 + lane];
        unsigned a1 = xb[(size_t)p1.x * 64 + lane];
        unsigned a2 = xb[(size_t)p2.x * 64 + lane];
        unsigned a3 = xb[(size_t)p3.x * 64 + lane];
        float w0 = __int_as_float(p0.y), w1 = __int_as_float(p1.y);
        float w2 = __int_as_float(p2.y), w3 = __int_as_float(p3.y);
        acc.x += bf_lo(a0) * w0; acc.y += bf_hi(a0) * w0;
        acc.x += bf_lo(a1) * w1; acc.y += bf_hi(a1) * w1;
        acc.x += bf_lo(a2) * w2; acc.y += bf_hi(a2) * w2;
        acc.x += bf_lo(a3) * w3; acc.y += bf_hi(a3) * w3;
    }
    for (; j < je; ++j) {
        int2 p0 = pair[j];
        unsigned a0 = xb[(size_t)p0.x * 64 + lane];
        float w0 = __int_as_float(p0.y);
        acc.x += bf_lo(a0) * w0; acc.y += bf_hi(a0) * w0;
    }
    xab[(size_t)gw * 64 + lane] = bf16rn(acc.x) | (bf16rn(acc.y) << 16);
}

// ---- GEMM1 (MFMA bf16): hb[M,128] = bf16(relu(xab @ W1t^T + b1)) ----------
// Block: 128 rows x 128 cols, K=128 staged once. LDS rows padded to 136 bf16
// (272B) -> 2-way bank aliasing only (free). 4 waves, each 32 rows x 128 cols.
__global__ __launch_bounds__(256) void k_gemm1(const unsigned* __restrict__ Ab,
                                               const unsigned* __restrict__ Wt,
                                               const float* __restrict__ bias,
                                               unsigned* __restrict__ Hb, int M) {
    __shared__ char smem[69632];            // As 128*272 + Bs 128*272
    char* Abase = smem;
    char* Bbase = smem + 34816;

    const int tid = threadIdx.x;
    const int r0 = blockIdx.x * 128;

    // stage A (xab rows r0..r0+127) and B (W1t), both 2048 uint4
#pragma unroll
    for (int s = 0; s < 8; ++s) {
        int l = tid + s * 256;
        int row = l >> 4, q = l & 15;
        // A: 16 uint4 per row of 64 uints
        uint4 va = *(const uint4*)(Ab + (size_t)(r0 + row) * 64 + q * 4);
        *(uint4*)(Abase + row * 272 + q * 16) = va;
        uint4 vb = *(const uint4*)(Wt + (size_t)row * 64 + q * 4);
        *(uint4*)(Bbase + row * 272 + q * 16) = vb;
    }
    __syncthreads();

    const int wv = tid >> 6, lane = tid & 63;
    const int quad = lane >> 4, mcol = lane & 15;

    f32x4 acc[2][8];
#pragma unroll
    for (int rt = 0; rt < 2; ++rt)
#pragma unroll
        for (int ct = 0; ct < 8; ++ct) acc[rt][ct] = (f32x4){0.f, 0.f, 0.f, 0.f};

#pragma unroll
    for (int ks = 0; ks < 4; ++ks) {
        bf16x8 a[2], b[8];
#pragma unroll
        for (int rt = 0; rt < 2; ++rt) {
            int row = wv * 32 + rt * 16 + mcol;
            a[rt] = *(const bf16x8*)(Abase + row * 272 + ks * 64 + quad * 16);
        }
#pragma unroll
        for (int ct = 0; ct < 8; ++ct) {
            int n = ct * 16 + mcol;
            b[ct] = *(const bf16x8*)(Bbase + n * 272 + ks * 64 + quad * 16);
        }
#pragma unroll
        for (int rt = 0; rt < 2; ++rt)
#pragma unroll
            for (int ct = 0; ct < 8; ++ct)
                acc[rt][ct] = __builtin_amdgcn_mfma_f32_16x16x32_bf16(
                    a[rt], b[ct], acc[rt][ct], 0, 0, 0);
    }
    __syncthreads();

    // epilogue: bias + relu -> bf16 into LDS [128][136], then coalesced store
    unsigned short* Hs = (unsigned short*)smem;
#pragma unroll
    for (int rt = 0; rt < 2; ++rt)
#pragma unroll
        for (int ct = 0; ct < 8; ++ct) {
            float bb = bias[ct * 16 + mcol];
#pragma unroll
            for (int r = 0; r < 4; ++r) {
                float v = acc[rt][ct][r] + bb;
                v = v > 0.f ? v : 0.f;
                int orow = wv * 32 + rt * 16 + quad * 4 + r;
                Hs[orow * 136 + ct * 16 + mcol] = (unsigned short)bf16rn(v);
            }
        }
    __syncthreads();

    int row = tid >> 1, hf = tid & 1;
    if (r0 + row < M) {
        const uint4* s4 = (const uint4*)(smem + row * 272 + hf * 128);
        uint4* d4 = (uint4*)(Hb + (size_t)(r0 + row) * 64 + hf * 32);
#pragma unroll
        for (int q = 0; q < 8; ++q) d4[q] = s4[q];
    }
}

// ---- GEMM2: Zb[M,40](bf16) = H(bf16)[M,128] @ W2[128,40] ------------------
__global__ __launch_bounds__(256) void k_gemm2(const unsigned* __restrict__ Hb,
                                               const float* __restrict__ W2,
                                               unsigned* __restrict__ Zb, int M) {
    __shared__ float hs[256][33];
    __shared__ float ws2[128][40];

    const int tid = threadIdx.x;
    const int row0 = blockIdx.x * 256;

    for (int idx = tid; idx < 128 * 40; idx += 256) ((float*)ws2)[idx] = W2[idx];

    float4 acc4[10];
#pragma unroll
    for (int j = 0; j < 10; ++j) acc4[j] = make_float4(0.f, 0.f, 0.f, 0.f);

    for (int kt = 0; kt < 4; ++kt) {
        __syncthreads();
#pragma unroll
        for (int s = 0; s < 16; ++s) {
            int l = tid + s * 256;          // 4096 uints per kt
            int row = l >> 4, q = l & 15;
            int rr = row0 + row;
            unsigned u = (rr < M) ? Hb[(size_t)rr * 64 + kt * 16 + q] : 0u;
            hs[row][2 * q]     = bf_lo(u);
            hs[row][2 * q + 1] = bf_hi(u);
        }
        __syncthreads();
#pragma unroll
        for (int k = 0; k < 32; ++k) {
            float xv = hs[tid][k];
            const float4* wrow = (const float4*)(&ws2[kt * 32 + k][0]);
#pragma unroll
            for (int j4 = 0; j4 < 10; ++j4) {
                float4 b = wrow[j4];
                acc4[j4].x += xv * b.x;
                acc4[j4].y += xv * b.y;
                acc4[j4].z += xv * b.z;
                acc4[j4].w += xv * b.w;
            }
        }
    }

    int rw = row0 + tid;
    if (rw < M) {
        unsigned pk[20];
#pragma unroll
        for (int j4 = 0; j4 < 10; ++j4) {
            pk[j4 * 2]     = bf16rn(acc4[j4].x) | (bf16rn(acc4[j4].y) << 16);
            pk[j4 * 2 + 1] = bf16rn(acc4[j4].z) | (bf16rn(acc4[j4].w) << 16);
        }
        uint4* zp = (uint4*)(&Zb[(size_t)rw * 20]);
#pragma unroll
        for (int q = 0; q < 5; ++q)
            zp[q] = make_uint4(pk[q * 4], pk[q * 4 + 1], pk[q * 4 + 2], pk[q * 4 + 3]);
    }
}

// ---- gather layer 2: out[v] = b2 + z[v]*dv^2 + sum z[r]*w -----------------
__global__ __launch_bounds__(256) void k_gather2(const unsigned* __restrict__ zb,
                                                 const int* __restrict__ rowptr,
                                                 const int2* __restrict__ pair,
                                                 const float* __restrict__ dis,
                                                 const float* __restrict__ b2,
                                                 float* __restrict__ out, int N) {
    int gw = (blockIdx.x * 256 + threadIdx.x) >> 6;
    int lane = threadIdx.x & 63;
    if (gw >= N) return;
    int sub = lane >> 5;
    int sl  = lane & 31;
    int f   = (sl < 20) ? sl : 19;

    float2 acc = make_float2(0.f, 0.f);
    float dv = dis[gw];
    if (sub == 0) {
        unsigned u = zb[(size_t)gw * 20 + f];
        float s = dv * dv;
        acc.x = bf_lo(u) * s; acc.y = bf_hi(u) * s;
    }

    int j = rowptr[gw], je = rowptr[gw + 1];
    for (; j + 3 < je; j += 4) {
        int2 pA = pair[j + sub];
        int2 pB = pair[j + 2 + sub];
        unsigned uA = zb[(size_t)pA.x * 20 + f];
        unsigned uB = zb[(size_t)pB.x * 20 + f];
        float wA = __int_as_float(pA.y), wB = __int_as_float(pB.y);
        acc.x += bf_lo(uA) * wA; acc.y += bf_hi(uA) * wA;
        acc.x += bf_lo(uB) * wB; acc.y += bf_hi(uB) * wB;
    }
    for (; j + 1 < je; j += 2) {
        int2 p = pair[j + sub];
        unsigned u = zb[(size_t)p.x * 20 + f];
        float w = __int_as_float(p.y);
        acc.x += bf_lo(u) * w; acc.y += bf_hi(u) * w;
    }
    if (j < je && sub == 0) {
        int2 p = pair[j];
        unsigned u = zb[(size_t)p.x * 20 + f];
        float w = __int_as_float(p.y);
        acc.x += bf_lo(u) * w; acc.y += bf_hi(u) * w;
    }

    float bx = __shfl(acc.x, sl + 32, 64);
    float by = __shfl(acc.y, sl + 32, 64);
    if (sub == 0 && sl < 20) {
        float2 bias = ((const float2*)b2)[sl];
        float2 res = make_float2(acc.x + bx + bias.x, acc.y + by + bias.y);
        ((float2*)(out + (size_t)gw * 40))[sl] = res;
    }
}

// ---------------------------------------------------------------------------
extern "C" void kernel_launch(void* const* d_in, const int* in_sizes, int n_in,
                              void* d_out, int out_size, void* d_ws, size_t ws_size,
                              hipStream_t stream) {
    const float* x  = (const float*)d_in[0];
    const int*   ei = (const int*)d_in[1];
    const float* W1 = (const float*)d_in[2];
    const float* b1 = (const float*)d_in[3];
    const float* W2 = (const float*)d_in[4];
    const float* b2 = (const float*)d_in[5];
    float* out = (float*)d_out;

    const int N = in_sizes[0] / 128;
    const int E = in_sizes[1] / 2;
    const int* row = ei;        // sources
    const int* col = ei + E;    // targets

    const int Np = (N + 255) & ~255;
    const int nb = (N + 255) / 256;    // must be <= 512

    // workspace layout (4-byte units), ~99 MB total
    int*      cnt    = (int*)d_ws;                       // Np
    int*      rowptr = cnt + Np;                         // Np + 256
    int*      cursor = rowptr + Np + 256;                // Np
    int*      bsum   = cursor + Np;                      // 1024
    float*    dis    = (float*)(bsum + 1024);            // Np
    unsigned* Wt     = (unsigned*)(dis + Np);            // 8192 (W1t bf16)
    int2*     pair   = (int2*)(Wt + 8192);               // E int2
    unsigned* xb     = (unsigned*)(pair + E);            // N*64 (bf16 x)
    unsigned* xab    = xb + (size_t)N * 64;              // N*64 (bf16 A*x)
    unsigned* hb     = xab + (size_t)N * 64;             // N*64 (bf16 h)
    unsigned* zb     = hb + (size_t)N * 64;              // N*20 (bf16 z)

    // degree / norm / CSC build
    hipMemsetAsync(cnt, 0, (size_t)Np * sizeof(int), stream);
    k_count<<<(E + 255) / 256, 256, 0, stream>>>(col, cnt, E);
    k_scan_block<<<nb, 256, 0, stream>>>(cnt, rowptr, bsum, dis, N);
    k_scan_bsum<<<1, 512, 0, stream>>>(bsum, nb);
    k_scan_add<<<nb, 256, 0, stream>>>(rowptr, cursor, bsum, N, E);
    k_fill<<<(E + 255) / 256, 256, 0, stream>>>(row, col, dis, cursor, pair, E);

    // conversions
    k_cvt<<<(N * 64 + 255) / 256, 256, 0, stream>>>(x, xb, N * 64);
    k_cvtW<<<32, 256, 0, stream>>>(W1, Wt);

    // layer 1: xab = bf16(A x) ; hb = bf16(relu(xab @ W1 + b1))  [MFMA]
    k_gather1<<<(N + 3) / 4, 256, 0, stream>>>(xb, rowptr, pair, dis, xab, N);
    k_gemm1<<<(N + 127) / 128, 256, 0, stream>>>(xab, Wt, b1, hb, N);

    // layer 2: zb = bf16(h @ W2) ; out = b2 + A z
    k_gemm2<<<(N + 255) / 256, 256, 0, stream>>>(hb, W2, zb, N);
    k_gather2<<<(N + 3) / 4, 256, 0, stream>>>(zb, rowptr, pair, dis, b2, out, N);
}

// Round 6
// 443.287 us; speedup vs baseline: 2.9922x; 1.0269x over previous
//
#include <hip/hip_runtime.h>
#include <hip/hip_bf16.h>

// ---------------------------------------------------------------------------
// 2-layer GCN, atomic-free CSC gather, bf16 payloads + bf16 MFMA GEMM1.
// Layer 1: h = relu((A x) @ W1 + b1)   [reassociated; A = norm adj + self]
// Layer 2: out = A (h @ W2) + b2
// CSC fill is a 2-pass LDS multisplit (bucket = 512 target nodes) to avoid
// the 8x full-line write amplification of the naive 8B scatter.
// ---------------------------------------------------------------------------

#define FB_SHIFT 9              // 512 nodes per bucket -> <=256 buckets for N<=131072

__device__ __forceinline__ unsigned bf16rn(float f) {
    unsigned x = __float_as_uint(f);
    unsigned r = ((x >> 16) & 1u) + 0x7fffu;   // RNE
    return (x + r) >> 16;
}
__device__ __forceinline__ float bf_lo(unsigned u) { return __uint_as_float(u << 16); }
__device__ __forceinline__ float bf_hi(unsigned u) { return __uint_as_float(u & 0xffff0000u); }

typedef __bf16 bf16x8 __attribute__((ext_vector_type(8)));
typedef float  f32x4  __attribute__((ext_vector_type(4)));

// ---- degree count ---------------------------------------------------------
__global__ __launch_bounds__(256) void k_count(const int* __restrict__ col,
                                               int* cnt, int E) {
    int e = blockIdx.x * 256 + threadIdx.x;
    if (e < E) atomicAdd(&cnt[col[e]], 1);
}

// ---- block scan of cnt -> rowptr(excl within block) + bsum + dis ----------
__global__ __launch_bounds__(256) void k_scan_block(const int* __restrict__ cnt,
                                                    int* __restrict__ rowptr,
                                                    int* __restrict__ bsum,
                                                    float* __restrict__ dis, int N) {
    __shared__ int s[256];
    int i = blockIdx.x * 256 + threadIdx.x;
    int v = (i < N) ? cnt[i] : 0;
    if (i < N) dis[i] = rsqrtf((float)(v + 1));   // +1 self-loop
    s[threadIdx.x] = v;
    __syncthreads();
#pragma unroll
    for (int off = 1; off < 256; off <<= 1) {
        int t = (threadIdx.x >= off) ? s[threadIdx.x - off] : 0;
        __syncthreads();
        s[threadIdx.x] += t;
        __syncthreads();
    }
    if (i < N) rowptr[i] = s[threadIdx.x] - v;
    if (threadIdx.x == 255) bsum[blockIdx.x] = s[255];
}

__global__ __launch_bounds__(512) void k_scan_bsum(int* bsum, int nb) {
    __shared__ int s[512];
    int t = threadIdx.x;
    int v = (t < nb) ? bsum[t] : 0;
    s[t] = v;
    __syncthreads();
#pragma unroll
    for (int off = 1; off < 512; off <<= 1) {
        int u = (t >= off) ? s[t - off] : 0;
        __syncthreads();
        s[t] += u;
        __syncthreads();
    }
    if (t < nb) bsum[t] = s[t] - v;
}

// also initializes per-node cursor and per-bucket bin cursor
__global__ __launch_bounds__(256) void k_scan_add(int* __restrict__ rowptr,
                                                  int* __restrict__ cursor,
                                                  int* __restrict__ bcur,
                                                  const int* __restrict__ bsum,
                                                  int N, int E) {
    int i = blockIdx.x * 256 + threadIdx.x;
    if (i < N) {
        int rp = rowptr[i] + bsum[i >> 8];
        rowptr[i] = rp;
        cursor[i] = rp;
        if ((i & ((1 << FB_SHIFT) - 1)) == 0) bcur[i >> FB_SHIFT] = rp;
    }
    if (i == 0) rowptr[N] = E;
}

// ---- multisplit pass A: bin edges by target bucket (512 nodes/bucket) -----
// Tile of 4096 edges per block: LDS histogram -> scan -> stage sorted ->
// one global atomic per (bucket,block) -> contiguous run writes.
__global__ __launch_bounds__(256) void k_binfill(const int* __restrict__ row,
                                                 const int* __restrict__ col,
                                                 int* __restrict__ bcur,
                                                 int2* __restrict__ bins, int E) {
    __shared__ int hist[256];
    __shared__ int scn[256];
    __shared__ int gbase[256];
    __shared__ int rcnt[256];
    __shared__ int2 stage[4096];

    const int tid = threadIdx.x;
    const int base = blockIdx.x * 4096;

    hist[tid] = 0;
    rcnt[tid] = 0;
    __syncthreads();

    int2 mye[16];
    int  myb[16];
#pragma unroll
    for (int k = 0; k < 16; ++k) {
        int e = base + k * 256 + tid;
        if (e < E) {
            int r = row[e], c = col[e];
            int b = c >> FB_SHIFT;
            mye[k] = make_int2(r, c);
            myb[k] = b;
            atomicAdd(&hist[b], 1);
        } else {
            myb[k] = -1;
        }
    }
    __syncthreads();

    // exclusive scan of hist -> scn
    int v = hist[tid];
    scn[tid] = v;
    __syncthreads();
#pragma unroll
    for (int off = 1; off < 256; off <<= 1) {
        int t = (tid >= off) ? scn[tid - off] : 0;
        __syncthreads();
        scn[tid] += t;
        __syncthreads();
    }
    int excl = scn[tid] - v;
    __syncthreads();
    scn[tid] = excl;
    __syncthreads();

    // stage: bucket-sorted within tile
#pragma unroll
    for (int k = 0; k < 16; ++k) {
        int b = myb[k];
        if (b >= 0) {
            int slot = scn[b] + atomicAdd(&rcnt[b], 1);
            stage[slot] = mye[k];
        }
    }

    // reserve global runs
    if (hist[tid] > 0) gbase[tid] = atomicAdd(&bcur[tid], hist[tid]);
    __syncthreads();

    int total = scn[255] + hist[255];
    for (int s = tid; s < total; s += 256) {
        int2 en = stage[s];
        int b = en.y >> FB_SHIFT;
        bins[gbase[b] + (s - scn[b])] = en;
    }
}

// ---- multisplit pass B: bucket-local scatter to exact CSC position --------
// One block per bucket: dst span (~64KB) stays in one XCD's L2.
__global__ __launch_bounds__(256) void k_fill2(const int2* __restrict__ bins,
                                               const int* __restrict__ rowptr,
                                               int* __restrict__ cursor,
                                               const float* __restrict__ dis,
                                               int2* __restrict__ pair,
                                               int N, int E) {
    int b = blockIdx.x;
    int n0 = b << FB_SHIFT;
    int n1 = (b + 1) << FB_SHIFT;
    int start = rowptr[n0];
    int end = (n1 >= N) ? E : rowptr[n1];
    for (int i = start + threadIdx.x; i < end; i += 256) {
        int2 en = bins[i];
        int r = en.x, c = en.y;
        int pos = atomicAdd(&cursor[c], 1);
        pair[pos] = make_int2(r, __float_as_int(dis[r] * dis[c]));
    }
}

// ---- convert x (fp32) -> xb (bf16x2 packed, 64 uints/row) -----------------
__global__ __launch_bounds__(256) void k_cvt(const float* __restrict__ x,
                                             unsigned* __restrict__ xb, int n64) {
    int i = blockIdx.x * 256 + threadIdx.x;
    if (i >= n64) return;
    float2 v = ((const float2*)x)[i];
    xb[i] = bf16rn(v.x) | (bf16rn(v.y) << 16);
}

// ---- W1 [128k][128n] fp32 -> W1t [n][k] bf16x2-packed (64 uints/row) ------
__global__ __launch_bounds__(256) void k_cvtW(const float* __restrict__ W1,
                                              unsigned* __restrict__ Wt) {
    int t = blockIdx.x * 256 + threadIdx.x;   // 8192 uints
    if (t >= 8192) return;
    int n = t >> 6, kk = (t & 63) * 2;
    unsigned lo = bf16rn(W1[(size_t)kk * 128 + n]);
    unsigned hi = bf16rn(W1[(size_t)(kk + 1) * 128 + n]);
    Wt[t] = lo | (hi << 16);
}

// ---- gather layer 1: xab[v] = bf16(x[v]*dv^2 + sum x[r]*w)  (wave/node) ---
__global__ __launch_bounds__(256) void k_gather1(const unsigned* __restrict__ xb,
                                                 const int* __restrict__ rowptr,
                                                 const int2* __restrict__ pair,
                                                 const float* __restrict__ dis,
                                                 unsigned* __restrict__ xab, int N) {
    int gw = (blockIdx.x * 256 + threadIdx.x) >> 6;
    int lane = threadIdx.x & 63;
    if (gw >= N) return;
    float dv = dis[gw];
    unsigned us = xb[(size_t)gw * 64 + lane];
    float s = dv * dv;
    float2 acc = make_float2(bf_lo(us) * s, bf_hi(us) * s);
    int j = rowptr[gw], je = rowptr[gw + 1];
    for (; j + 3 < je; j += 4) {
        int2 p0 = pair[j], p1 = pair[j + 1], p2 = pair[j + 2], p3 = pair[j + 3];
        unsigned a0 = xb[(size_t)p0.x * 64 + lane];
        unsigned a1 = xb[(size_t)p1.x * 64 + lane];
        unsigned a2 = xb[(size_t)p2.x * 64 + lane];
        unsigned a3 = xb[(size_t)p3.x * 64 + lane];
        float w0 = __int_as_float(p0.y), w1 = __int_as_float(p1.y);
        float w2 = __int_as_float(p2.y), w3 = __int_as_float(p3.y);
        acc.x += bf_lo(a0) * w0; acc.y += bf_hi(a0) * w0;
        acc.x += bf_lo(a1) * w1; acc.y += bf_hi(a1) * w1;
        acc.x += bf_lo(a2) * w2; acc.y += bf_hi(a2) * w2;
        acc.x += bf_lo(a3) * w3; acc.y += bf_hi(a3) * w3;
    }
    for (; j < je; ++j) {
        int2 p0 = pair[j];
        unsigned a0 = xb[(size_t)p0.x * 64 + lane];
        float w0 = __int_as_float(p0.y);
        acc.x += bf_lo(a0) * w0; acc.y += bf_hi(a0) * w0;
    }
    xab[(size_t)gw * 64 + lane] = bf16rn(acc.x) | (bf16rn(acc.y) << 16);
}

// ---- GEMM1 (MFMA bf16): hb[M,128] = bf16(relu(xab @ W1t^T + b1)) ----------
__global__ __launch_bounds__(256) void k_gemm1(const unsigned* __restrict__ Ab,
                                               const unsigned* __restrict__ Wt,
                                               const float* __restrict__ bias,
                                               unsigned* __restrict__ Hb, int M) {
    __shared__ char smem[69632];            // As 128*272 + Bs 128*272
    char* Abase = smem;
    char* Bbase = smem + 34816;

    const int tid = threadIdx.x;
    const int r0 = blockIdx.x * 128;

#pragma unroll
    for (int s = 0; s < 8; ++s) {
        int l = tid + s * 256;
        int row = l >> 4, q = l & 15;
        uint4 va = *(const uint4*)(Ab + (size_t)(r0 + row) * 64 + q * 4);
        *(uint4*)(Abase + row * 272 + q * 16) = va;
        uint4 vb = *(const uint4*)(Wt + (size_t)row * 64 + q * 4);
        *(uint4*)(Bbase + row * 272 + q * 16) = vb;
    }
    __syncthreads();

    const int wv = tid >> 6, lane = tid & 63;
    const int quad = lane >> 4, mcol = lane & 15;

    f32x4 acc[2][8];
#pragma unroll
    for (int rt = 0; rt < 2; ++rt)
#pragma unroll
        for (int ct = 0; ct < 8; ++ct) acc[rt][ct] = (f32x4){0.f, 0.f, 0.f, 0.f};

#pragma unroll
    for (int ks = 0; ks < 4; ++ks) {
        bf16x8 a[2], b[8];
#pragma unroll
        for (int rt = 0; rt < 2; ++rt) {
            int row = wv * 32 + rt * 16 + mcol;
            a[rt] = *(const bf16x8*)(Abase + row * 272 + ks * 64 + quad * 16);
        }
#pragma unroll
        for (int ct = 0; ct < 8; ++ct) {
            int n = ct * 16 + mcol;
            b[ct] = *(const bf16x8*)(Bbase + n * 272 + ks * 64 + quad * 16);
        }
#pragma unroll
        for (int rt = 0; rt < 2; ++rt)
#pragma unroll
            for (int ct = 0; ct < 8; ++ct)
                acc[rt][ct] = __builtin_amdgcn_mfma_f32_16x16x32_bf16(
                    a[rt], b[ct], acc[rt][ct], 0, 0, 0);
    }
    __syncthreads();

    unsigned short* Hs = (unsigned short*)smem;
#pragma unroll
    for (int rt = 0; rt < 2; ++rt)
#pragma unroll
        for (int ct = 0; ct < 8; ++ct) {
            float bb = bias[ct * 16 + mcol];
#pragma unroll
            for (int r = 0; r < 4; ++r) {
                float v = acc[rt][ct][r] + bb;
                v = v > 0.f ? v : 0.f;
                int orow = wv * 32 + rt * 16 + quad * 4 + r;
                Hs[orow * 136 + ct * 16 + mcol] = (unsigned short)bf16rn(v);
            }
        }
    __syncthreads();

    int row = tid >> 1, hf = tid & 1;
    if (r0 + row < M) {
        const uint4* s4 = (const uint4*)(smem + row * 272 + hf * 128);
        uint4* d4 = (uint4*)(Hb + (size_t)(r0 + row) * 64 + hf * 32);
#pragma unroll
        for (int q = 0; q < 8; ++q) d4[q] = s4[q];
    }
}

// ---- GEMM2: Zb[M,40](bf16) = H(bf16)[M,128] @ W2[128,40] ------------------
__global__ __launch_bounds__(256) void k_gemm2(const unsigned* __restrict__ Hb,
                                               const float* __restrict__ W2,
                                               unsigned* __restrict__ Zb, int M) {
    __shared__ float hs[256][33];
    __shared__ float ws2[128][40];

    const int tid = threadIdx.x;
    const int row0 = blockIdx.x * 256;

    for (int idx = tid; idx < 128 * 40; idx += 256) ((float*)ws2)[idx] = W2[idx];

    float4 acc4[10];
#pragma unroll
    for (int j = 0; j < 10; ++j) acc4[j] = make_float4(0.f, 0.f, 0.f, 0.f);

    for (int kt = 0; kt < 4; ++kt) {
        __syncthreads();
#pragma unroll
        for (int s = 0; s < 16; ++s) {
            int l = tid + s * 256;
            int row = l >> 4, q = l & 15;
            int rr = row0 + row;
            unsigned u = (rr < M) ? Hb[(size_t)rr * 64 + kt * 16 + q] : 0u;
            hs[row][2 * q]     = bf_lo(u);
            hs[row][2 * q + 1] = bf_hi(u);
        }
        __syncthreads();
#pragma unroll
        for (int k = 0; k < 32; ++k) {
            float xv = hs[tid][k];
            const float4* wrow = (const float4*)(&ws2[kt * 32 + k][0]);
#pragma unroll
            for (int j4 = 0; j4 < 10; ++j4) {
                float4 b = wrow[j4];
                acc4[j4].x += xv * b.x;
                acc4[j4].y += xv * b.y;
                acc4[j4].z += xv * b.z;
                acc4[j4].w += xv * b.w;
            }
        }
    }

    int rw = row0 + tid;
    if (rw < M) {
        unsigned pk[20];
#pragma unroll
        for (int j4 = 0; j4 < 10; ++j4) {
            pk[j4 * 2]     = bf16rn(acc4[j4].x) | (bf16rn(acc4[j4].y) << 16);
            pk[j4 * 2 + 1] = bf16rn(acc4[j4].z) | (bf16rn(acc4[j4].w) << 16);
        }
        uint4* zp = (uint4*)(&Zb[(size_t)rw * 20]);
#pragma unroll
        for (int q = 0; q < 5; ++q)
            zp[q] = make_uint4(pk[q * 4], pk[q * 4 + 1], pk[q * 4 + 2], pk[q * 4 + 3]);
    }
}

// ---- gather layer 2: out[v] = b2 + z[v]*dv^2 + sum z[r]*w -----------------
__global__ __launch_bounds__(256) void k_gather2(const unsigned* __restrict__ zb,
                                                 const int* __restrict__ rowptr,
                                                 const int2* __restrict__ pair,
                                                 const float* __restrict__ dis,
                                                 const float* __restrict__ b2,
                                                 float* __restrict__ out, int N) {
    int gw = (blockIdx.x * 256 + threadIdx.x) >> 6;
    int lane = threadIdx.x & 63;
    if (gw >= N) return;
    int sub = lane >> 5;
    int sl  = lane & 31;
    int f   = (sl < 20) ? sl : 19;

    float2 acc = make_float2(0.f, 0.f);
    float dv = dis[gw];
    if (sub == 0) {
        unsigned u = zb[(size_t)gw * 20 + f];
        float s = dv * dv;
        acc.x = bf_lo(u) * s; acc.y = bf_hi(u) * s;
    }

    int j = rowptr[gw], je = rowptr[gw + 1];
    for (; j + 3 < je; j += 4) {
        int2 pA = pair[j + sub];
        int2 pB = pair[j + 2 + sub];
        unsigned uA = zb[(size_t)pA.x * 20 + f];
        unsigned uB = zb[(size_t)pB.x * 20 + f];
        float wA = __int_as_float(pA.y), wB = __int_as_float(pB.y);
        acc.x += bf_lo(uA) * wA; acc.y += bf_hi(uA) * wA;
        acc.x += bf_lo(uB) * wB; acc.y += bf_hi(uB) * wB;
    }
    for (; j + 1 < je; j += 2) {
        int2 p = pair[j + sub];
        unsigned u = zb[(size_t)p.x * 20 + f];
        float w = __int_as_float(p.y);
        acc.x += bf_lo(u) * w; acc.y += bf_hi(u) * w;
    }
    if (j < je && sub == 0) {
        int2 p = pair[j];
        unsigned u = zb[(size_t)p.x * 20 + f];
        float w = __int_as_float(p.y);
        acc.x += bf_lo(u) * w; acc.y += bf_hi(u) * w;
    }

    float bx = __shfl(acc.x, sl + 32, 64);
    float by = __shfl(acc.y, sl + 32, 64);
    if (sub == 0 && sl < 20) {
        float2 bias = ((const float2*)b2)[sl];
        float2 res = make_float2(acc.x + bx + bias.x, acc.y + by + bias.y);
        ((float2*)(out + (size_t)gw * 40))[sl] = res;
    }
}

// ---------------------------------------------------------------------------
extern "C" void kernel_launch(void* const* d_in, const int* in_sizes, int n_in,
                              void* d_out, int out_size, void* d_ws, size_t ws_size,
                              hipStream_t stream) {
    const float* x  = (const float*)d_in[0];
    const int*   ei = (const int*)d_in[1];
    const float* W1 = (const float*)d_in[2];
    const float* b1 = (const float*)d_in[3];
    const float* W2 = (const float*)d_in[4];
    const float* b2 = (const float*)d_in[5];
    float* out = (float*)d_out;

    const int N = in_sizes[0] / 128;
    const int E = in_sizes[1] / 2;
    const int* row = ei;        // sources
    const int* col = ei + E;    // targets

    const int Np = (N + 255) & ~255;
    const int nb = (N + 255) / 256;            // must be <= 512
    const int nbuck = (N + (1 << FB_SHIFT) - 1) >> FB_SHIFT;   // <= 256

    // workspace layout (4-byte units), ~99 MB total
    int*      cnt    = (int*)d_ws;                       // Np
    int*      rowptr = cnt + Np;                         // Np + 256
    int*      cursor = rowptr + Np + 256;                // Np
    int*      bsum   = cursor + Np;                      // 1024
    int*      bcur   = bsum + 1024;                      // 256
    float*    dis    = (float*)(bcur + 256);             // Np
    unsigned* Wt     = (unsigned*)(dis + Np);            // 8192 (W1t bf16)
    int2*     pair   = (int2*)(Wt + 8192);               // E int2
    unsigned* xb     = (unsigned*)(pair + E);            // N*64 (bf16 x)
    unsigned* xab    = xb + (size_t)N * 64;              // N*64 (bf16 A*x)
    unsigned* hb     = xab + (size_t)N * 64;             // N*64 (bf16 h)
    unsigned* zb     = hb + (size_t)N * 64;              // N*20 (bf16 z)
    int2*     bins   = (int2*)xab;    // alias: dead before k_gather1 writes xab

    // degree / norm / CSC build
    hipMemsetAsync(cnt, 0, (size_t)Np * sizeof(int), stream);
    k_count<<<(E + 255) / 256, 256, 0, stream>>>(col, cnt, E);
    k_scan_block<<<nb, 256, 0, stream>>>(cnt, rowptr, bsum, dis, N);
    k_scan_bsum<<<1, 512, 0, stream>>>(bsum, nb);
    k_scan_add<<<nb, 256, 0, stream>>>(rowptr, cursor, bcur, bsum, N, E);
    k_binfill<<<(E + 4095) / 4096, 256, 0, stream>>>(row, col, bcur, bins, E);
    k_fill2<<<nbuck, 256, 0, stream>>>(bins, rowptr, cursor, dis, pair, N, E);

    // conversions
    k_cvt<<<(N * 64 + 255) / 256, 256, 0, stream>>>(x, xb, N * 64);
    k_cvtW<<<32, 256, 0, stream>>>(W1, Wt);

    // layer 1: xab = bf16(A x) ; hb = bf16(relu(xab @ W1 + b1))  [MFMA]
    k_gather1<<<(N + 3) / 4, 256, 0, stream>>>(xb, rowptr, pair, dis, xab, N);
    k_gemm1<<<(N + 127) / 128, 256, 0, stream>>>(xab, Wt, b1, hb, N);

    // layer 2: zb = bf16(h @ W2) ; out = b2 + A z
    k_gemm2<<<(N + 255) / 256, 256, 0, stream>>>(hb, W2, zb, N);
    k_gather2<<<(N + 3) / 4, 256, 0, stream>>>(zb, rowptr, pair, dis, b2, out, N);
}

// Round 8
// 432.788 us; speedup vs baseline: 3.0648x; 1.0243x over previous
//
#include <hip/hip_runtime.h>
#include <hip/hip_bf16.h>

// ---------------------------------------------------------------------------
// 2-layer GCN, atomic-free CSC gather, bf16 payloads + bf16 MFMA GEMM1.
// Layer 1: h = relu((A x) @ W1 + b1)   [reassociated; A = norm adj + self]
// Layer 2: out = A (h @ W2) + b2
// CSC fill is a 2-pass LDS multisplit (bucket = 512 target nodes).
// gather1: wave-per-node, 8 gathers in flight (r6 structure, deeper unroll;
// r7's half-wave shfl variant failed correctness and was reverted).
// ---------------------------------------------------------------------------

#define FB_SHIFT 9              // 512 nodes per bucket -> <=256 buckets for N<=131072

__device__ __forceinline__ unsigned bf16rn(float f) {
    unsigned x = __float_as_uint(f);
    unsigned r = ((x >> 16) & 1u) + 0x7fffu;   // RNE
    return (x + r) >> 16;
}
__device__ __forceinline__ float bf_lo(unsigned u) { return __uint_as_float(u << 16); }
__device__ __forceinline__ float bf_hi(unsigned u) { return __uint_as_float(u & 0xffff0000u); }

typedef __bf16 bf16x8 __attribute__((ext_vector_type(8)));
typedef float  f32x4  __attribute__((ext_vector_type(4)));

// ---- degree count ---------------------------------------------------------
__global__ __launch_bounds__(256) void k_count(const int* __restrict__ col,
                                               int* cnt, int E) {
    int e = blockIdx.x * 256 + threadIdx.x;
    if (e < E) atomicAdd(&cnt[col[e]], 1);
}

// ---- block scan of cnt -> rowptr(excl within block) + bsum + dis ----------
__global__ __launch_bounds__(256) void k_scan_block(const int* __restrict__ cnt,
                                                    int* __restrict__ rowptr,
                                                    int* __restrict__ bsum,
                                                    float* __restrict__ dis, int N) {
    __shared__ int s[256];
    int i = blockIdx.x * 256 + threadIdx.x;
    int v = (i < N) ? cnt[i] : 0;
    if (i < N) dis[i] = rsqrtf((float)(v + 1));   // +1 self-loop
    s[threadIdx.x] = v;
    __syncthreads();
#pragma unroll
    for (int off = 1; off < 256; off <<= 1) {
        int t = (threadIdx.x >= off) ? s[threadIdx.x - off] : 0;
        __syncthreads();
        s[threadIdx.x] += t;
        __syncthreads();
    }
    if (i < N) rowptr[i] = s[threadIdx.x] - v;
    if (threadIdx.x == 255) bsum[blockIdx.x] = s[255];
}

__global__ __launch_bounds__(512) void k_scan_bsum(int* bsum, int nb) {
    __shared__ int s[512];
    int t = threadIdx.x;
    int v = (t < nb) ? bsum[t] : 0;
    s[t] = v;
    __syncthreads();
#pragma unroll
    for (int off = 1; off < 512; off <<= 1) {
        int u = (t >= off) ? s[t - off] : 0;
        __syncthreads();
        s[t] += u;
        __syncthreads();
    }
    if (t < nb) bsum[t] = s[t] - v;
}

// also initializes per-node cursor and per-bucket bin cursor
__global__ __launch_bounds__(256) void k_scan_add(int* __restrict__ rowptr,
                                                  int* __restrict__ cursor,
                                                  int* __restrict__ bcur,
                                                  const int* __restrict__ bsum,
                                                  int N, int E) {
    int i = blockIdx.x * 256 + threadIdx.x;
    if (i < N) {
        int rp = rowptr[i] + bsum[i >> 8];
        rowptr[i] = rp;
        cursor[i] = rp;
        if ((i & ((1 << FB_SHIFT) - 1)) == 0) bcur[i >> FB_SHIFT] = rp;
    }
    if (i == 0) rowptr[N] = E;
}

// ---- multisplit pass A: bin edges by target bucket (512 nodes/bucket) -----
__global__ __launch_bounds__(256) void k_binfill(const int* __restrict__ row,
                                                 const int* __restrict__ col,
                                                 int* __restrict__ bcur,
                                                 int2* __restrict__ bins, int E) {
    __shared__ int hist[256];
    __shared__ int scn[256];
    __shared__ int gbase[256];
    __shared__ int rcnt[256];
    __shared__ int2 stage[4096];

    const int tid = threadIdx.x;
    const int base = blockIdx.x * 4096;

    hist[tid] = 0;
    rcnt[tid] = 0;
    __syncthreads();

    int2 mye[16];
    int  myb[16];
#pragma unroll
    for (int k = 0; k < 16; ++k) {
        int e = base + k * 256 + tid;
        if (e < E) {
            int r = row[e], c = col[e];
            int b = c >> FB_SHIFT;
            mye[k] = make_int2(r, c);
            myb[k] = b;
            atomicAdd(&hist[b], 1);
        } else {
            myb[k] = -1;
        }
    }
    __syncthreads();

    int v = hist[tid];
    scn[tid] = v;
    __syncthreads();
#pragma unroll
    for (int off = 1; off < 256; off <<= 1) {
        int t = (tid >= off) ? scn[tid - off] : 0;
        __syncthreads();
        scn[tid] += t;
        __syncthreads();
    }
    int excl = scn[tid] - v;
    __syncthreads();
    scn[tid] = excl;
    __syncthreads();

#pragma unroll
    for (int k = 0; k < 16; ++k) {
        int b = myb[k];
        if (b >= 0) {
            int slot = scn[b] + atomicAdd(&rcnt[b], 1);
            stage[slot] = mye[k];
        }
    }

    if (hist[tid] > 0) gbase[tid] = atomicAdd(&bcur[tid], hist[tid]);
    __syncthreads();

    int total = scn[255] + hist[255];
    for (int s = tid; s < total; s += 256) {
        int2 en = stage[s];
        int b = en.y >> FB_SHIFT;
        bins[gbase[b] + (s - scn[b])] = en;
    }
}

// ---- multisplit pass B: bucket-local scatter to exact CSC position --------
__global__ __launch_bounds__(256) void k_fill2(const int2* __restrict__ bins,
                                               const int* __restrict__ rowptr,
                                               int* __restrict__ cursor,
                                               const float* __restrict__ dis,
                                               int2* __restrict__ pair,
                                               int N, int E) {
    int b = blockIdx.x;
    int n0 = b << FB_SHIFT;
    int n1 = (b + 1) << FB_SHIFT;
    int start = rowptr[n0];
    int end = (n1 >= N) ? E : rowptr[n1];
    for (int i = start + threadIdx.x; i < end; i += 256) {
        int2 en = bins[i];
        int r = en.x, c = en.y;
        int pos = atomicAdd(&cursor[c], 1);
        pair[pos] = make_int2(r, __float_as_int(dis[r] * dis[c]));
    }
}

// ---- convert x (fp32) -> xb (bf16x2 packed, 64 uints/row) -----------------
__global__ __launch_bounds__(256) void k_cvt(const float* __restrict__ x,
                                             unsigned* __restrict__ xb, int n64) {
    int i = blockIdx.x * 256 + threadIdx.x;
    if (i >= n64) return;
    float2 v = ((const float2*)x)[i];
    xb[i] = bf16rn(v.x) | (bf16rn(v.y) << 16);
}

// ---- W1 [128k][128n] fp32 -> W1t [n][k] bf16x2-packed (64 uints/row) ------
__global__ __launch_bounds__(256) void k_cvtW(const float* __restrict__ W1,
                                              unsigned* __restrict__ Wt) {
    int t = blockIdx.x * 256 + threadIdx.x;   // 8192 uints
    if (t >= 8192) return;
    int n = t >> 6, kk = (t & 63) * 2;
    unsigned lo = bf16rn(W1[(size_t)kk * 128 + n]);
    unsigned hi = bf16rn(W1[(size_t)(kk + 1) * 128 + n]);
    Wt[t] = lo | (hi << 16);
}

// ---- gather layer 1: xab[v] = bf16(x[v]*dv^2 + sum x[r]*w)  (wave/node) ---
// r6-proven structure, 8 gathers in flight; 4-wide then 1-wide tail.
__global__ __launch_bounds__(256) void k_gather1(const unsigned* __restrict__ xb,
                                                 const int* __restrict__ rowptr,
                                                 const int2* __restrict__ pair,
                                                 const float* __restrict__ dis,
                                                 unsigned* __restrict__ xab, int N) {
    int gw = (blockIdx.x * 256 + threadIdx.x) >> 6;
    int lane = threadIdx.x & 63;
    if (gw >= N) return;
    float dv = dis[gw];
    unsigned us = xb[(size_t)gw * 64 + lane];
    float s = dv * dv;
    float2 acc = make_float2(bf_lo(us) * s, bf_hi(us) * s);
    int j = rowptr[gw], je = rowptr[gw + 1];

    for (; j + 7 < je; j += 8) {
        int2 p0 = pair[j],     p1 = pair[j + 1], p2 = pair[j + 2], p3 = pair[j + 3];
        int2 p4 = pair[j + 4], p5 = pair[j + 5], p6 = pair[j + 6], p7 = pair[j + 7];
        unsigned a0 = xb[(size_t)p0.x * 64 + lane];
        unsigned a1 = xb[(size_t)p1.x * 64 + lane];
        unsigned a2 = xb[(size_t)p2.x * 64 + lane];
        unsigned a3 = xb[(size_t)p3.x * 64 + lane];
        unsigned a4 = xb[(size_t)p4.x * 64 + lane];
        unsigned a5 = xb[(size_t)p5.x * 64 + lane];
        unsigned a6 = xb[(size_t)p6.x * 64 + lane];
        unsigned a7 = xb[(size_t)p7.x * 64 + lane];
        float w0 = __int_as_float(p0.y), w1 = __int_as_float(p1.y);
        float w2 = __int_as_float(p2.y), w3 = __int_as_float(p3.y);
        float w4 = __int_as_float(p4.y), w5 = __int_as_float(p5.y);
        float w6 = __int_as_float(p6.y), w7 = __int_as_float(p7.y);
        acc.x += bf_lo(a0) * w0; acc.y += bf_hi(a0) * w0;
        acc.x += bf_lo(a1) * w1; acc.y += bf_hi(a1) * w1;
        acc.x += bf_lo(a2) * w2; acc.y += bf_hi(a2) * w2;
        acc.x += bf_lo(a3) * w3; acc.y += bf_hi(a3) * w3;
        acc.x += bf_lo(a4) * w4; acc.y += bf_hi(a4) * w4;
        acc.x += bf_lo(a5) * w5; acc.y += bf_hi(a5) * w5;
        acc.x += bf_lo(a6) * w6; acc.y += bf_hi(a6) * w6;
        acc.x += bf_lo(a7) * w7; acc.y += bf_hi(a7) * w7;
    }
    for (; j + 3 < je; j += 4) {
        int2 p0 = pair[j], p1 = pair[j + 1], p2 = pair[j + 2], p3 = pair[j + 3];
        unsigned a0 = xb[(size_t)p0.x * 64 + lane];
        unsigned a1 = xb[(size_t)p1.x * 64 + lane];
        unsigned a2 = xb[(size_t)p2.x * 64 + lane];
        unsigned a3 = xb[(size_t)p3.x * 64 + lane];
        float w0 = __int_as_float(p0.y), w1 = __int_as_float(p1.y);
        float w2 = __int_as_float(p2.y), w3 = __int_as_float(p3.y);
        acc.x += bf_lo(a0) * w0; acc.y += bf_hi(a0) * w0;
        acc.x += bf_lo(a1) * w1; acc.y += bf_hi(a1) * w1;
        acc.x += bf_lo(a2) * w2; acc.y += bf_hi(a2) * w2;
        acc.x += bf_lo(a3) * w3; acc.y += bf_hi(a3) * w3;
    }
    for (; j < je; ++j) {
        int2 p0 = pair[j];
        unsigned a0 = xb[(size_t)p0.x * 64 + lane];
        float w0 = __int_as_float(p0.y);
        acc.x += bf_lo(a0) * w0; acc.y += bf_hi(a0) * w0;
    }
    xab[(size_t)gw * 64 + lane] = bf16rn(acc.x) | (bf16rn(acc.y) << 16);
}

// ---- GEMM1 (MFMA bf16): hb[M,128] = bf16(relu(xab @ W1t^T + b1)) ----------
__global__ __launch_bounds__(256) void k_gemm1(const unsigned* __restrict__ Ab,
                                               const unsigned* __restrict__ Wt,
                                               const float* __restrict__ bias,
                                               unsigned* __restrict__ Hb, int M) {
    __shared__ char smem[69632];            // As 128*272 + Bs 128*272
    char* Abase = smem;
    char* Bbase = smem + 34816;

    const int tid = threadIdx.x;
    const int r0 = blockIdx.x * 128;

#pragma unroll
    for (int s = 0; s < 8; ++s) {
        int l = tid + s * 256;
        int row = l >> 4, q = l & 15;
        uint4 va = *(const uint4*)(Ab + (size_t)(r0 + row) * 64 + q * 4);
        *(uint4*)(Abase + row * 272 + q * 16) = va;
        uint4 vb = *(const uint4*)(Wt + (size_t)row * 64 + q * 4);
        *(uint4*)(Bbase + row * 272 + q * 16) = vb;
    }
    __syncthreads();

    const int wv = tid >> 6, lane = tid & 63;
    const int quad = lane >> 4, mcol = lane & 15;

    f32x4 acc[2][8];
#pragma unroll
    for (int rt = 0; rt < 2; ++rt)
#pragma unroll
        for (int ct = 0; ct < 8; ++ct) acc[rt][ct] = (f32x4){0.f, 0.f, 0.f, 0.f};

#pragma unroll
    for (int ks = 0; ks < 4; ++ks) {
        bf16x8 a[2], b[8];
#pragma unroll
        for (int rt = 0; rt < 2; ++rt) {
            int row = wv * 32 + rt * 16 + mcol;
            a[rt] = *(const bf16x8*)(Abase + row * 272 + ks * 64 + quad * 16);
        }
#pragma unroll
        for (int ct = 0; ct < 8; ++ct) {
            int n = ct * 16 + mcol;
            b[ct] = *(const bf16x8*)(Bbase + n * 272 + ks * 64 + quad * 16);
        }
#pragma unroll
        for (int rt = 0; rt < 2; ++rt)
#pragma unroll
            for (int ct = 0; ct < 8; ++ct)
                acc[rt][ct] = __builtin_amdgcn_mfma_f32_16x16x32_bf16(
                    a[rt], b[ct], acc[rt][ct], 0, 0, 0);
    }
    __syncthreads();

    unsigned short* Hs = (unsigned short*)smem;
#pragma unroll
    for (int rt = 0; rt < 2; ++rt)
#pragma unroll
        for (int ct = 0; ct < 8; ++ct) {
            float bb = bias[ct * 16 + mcol];
#pragma unroll
            for (int r = 0; r < 4; ++r) {
                float v = acc[rt][ct][r] + bb;
                v = v > 0.f ? v : 0.f;
                int orow = wv * 32 + rt * 16 + quad * 4 + r;
                Hs[orow * 136 + ct * 16 + mcol] = (unsigned short)bf16rn(v);
            }
        }
    __syncthreads();

    int row = tid >> 1, hf = tid & 1;
    if (r0 + row < M) {
        const uint4* s4 = (const uint4*)(smem + row * 272 + hf * 128);
        uint4* d4 = (uint4*)(Hb + (size_t)(r0 + row) * 64 + hf * 32);
#pragma unroll
        for (int q = 0; q < 8; ++q) d4[q] = s4[q];
    }
}

// ---- GEMM2: Zb[M,40](bf16) = H(bf16)[M,128] @ W2[128,40] ------------------
__global__ __launch_bounds__(256) void k_gemm2(const unsigned* __restrict__ Hb,
                                               const float* __restrict__ W2,
                                               unsigned* __restrict__ Zb, int M) {
    __shared__ float hs[256][33];
    __shared__ float ws2[128][40];

    const int tid = threadIdx.x;
    const int row0 = blockIdx.x * 256;

    for (int idx = tid; idx < 128 * 40; idx += 256) ((float*)ws2)[idx] = W2[idx];

    float4 acc4[10];
#pragma unroll
    for (int j = 0; j < 10; ++j) acc4[j] = make_float4(0.f, 0.f, 0.f, 0.f);

    for (int kt = 0; kt < 4; ++kt) {
        __syncthreads();
#pragma unroll
        for (int s = 0; s < 16; ++s) {
            int l = tid + s * 256;
            int row = l >> 4, q = l & 15;
            int rr = row0 + row;
            unsigned u = (rr < M) ? Hb[(size_t)rr * 64 + kt * 16 + q] : 0u;
            hs[row][2 * q]     = bf_lo(u);
            hs[row][2 * q + 1] = bf_hi(u);
        }
        __syncthreads();
#pragma unroll
        for (int k = 0; k < 32; ++k) {
            float xv = hs[tid][k];
            const float4* wrow = (const float4*)(&ws2[kt * 32 + k][0]);
#pragma unroll
            for (int j4 = 0; j4 < 10; ++j4) {
                float4 b = wrow[j4];
                acc4[j4].x += xv * b.x;
                acc4[j4].y += xv * b.y;
                acc4[j4].z += xv * b.z;
                acc4[j4].w += xv * b.w;
            }
        }
    }

    int rw = row0 + tid;
    if (rw < M) {
        unsigned pk[20];
#pragma unroll
        for (int j4 = 0; j4 < 10; ++j4) {
            pk[j4 * 2]     = bf16rn(acc4[j4].x) | (bf16rn(acc4[j4].y) << 16);
            pk[j4 * 2 + 1] = bf16rn(acc4[j4].z) | (bf16rn(acc4[j4].w) << 16);
        }
        uint4* zp = (uint4*)(&Zb[(size_t)rw * 20]);
#pragma unroll
        for (int q = 0; q < 5; ++q)
            zp[q] = make_uint4(pk[q * 4], pk[q * 4 + 1], pk[q * 4 + 2], pk[q * 4 + 3]);
    }
}

// ---- gather layer 2: out[v] = b2 + z[v]*dv^2 + sum z[r]*w -----------------
__global__ __launch_bounds__(256) void k_gather2(const unsigned* __restrict__ zb,
                                                 const int* __restrict__ rowptr,
                                                 const int2* __restrict__ pair,
                                                 const float* __restrict__ dis,
                                                 const float* __restrict__ b2,
                                                 float* __restrict__ out, int N) {
    int gw = (blockIdx.x * 256 + threadIdx.x) >> 6;
    int lane = threadIdx.x & 63;
    if (gw >= N) return;
    int sub = lane >> 5;
    int sl  = lane & 31;
    int f   = (sl < 20) ? sl : 19;

    float2 acc = make_float2(0.f, 0.f);
    float dv = dis[gw];
    if (sub == 0) {
        unsigned u = zb[(size_t)gw * 20 + f];
        float s = dv * dv;
        acc.x = bf_lo(u) * s; acc.y = bf_hi(u) * s;
    }

    int j = rowptr[gw], je = rowptr[gw + 1];
    for (; j + 3 < je; j += 4) {
        int2 pA = pair[j + sub];
        int2 pB = pair[j + 2 + sub];
        unsigned uA = zb[(size_t)pA.x * 20 + f];
        unsigned uB = zb[(size_t)pB.x * 20 + f];
        float wA = __int_as_float(pA.y), wB = __int_as_float(pB.y);
        acc.x += bf_lo(uA) * wA; acc.y += bf_hi(uA) * wA;
        acc.x += bf_lo(uB) * wB; acc.y += bf_hi(uB) * wB;
    }
    for (; j + 1 < je; j += 2) {
        int2 p = pair[j + sub];
        unsigned u = zb[(size_t)p.x * 20 + f];
        float w = __int_as_float(p.y);
        acc.x += bf_lo(u) * w; acc.y += bf_hi(u) * w;
    }
    if (j < je && sub == 0) {
        int2 p = pair[j];
        unsigned u = zb[(size_t)p.x * 20 + f];
        float w = __int_as_float(p.y);
        acc.x += bf_lo(u) * w; acc.y += bf_hi(u) * w;
    }

    float bx = __shfl(acc.x, sl + 32, 64);
    float by = __shfl(acc.y, sl + 32, 64);
    if (sub == 0 && sl < 20) {
        float2 bias = ((const float2*)b2)[sl];
        float2 res = make_float2(acc.x + bx + bias.x, acc.y + by + bias.y);
        ((float2*)(out + (size_t)gw * 40))[sl] = res;
    }
}

// ---------------------------------------------------------------------------
extern "C" void kernel_launch(void* const* d_in, const int* in_sizes, int n_in,
                              void* d_out, int out_size, void* d_ws, size_t ws_size,
                              hipStream_t stream) {
    const float* x  = (const float*)d_in[0];
    const int*   ei = (const int*)d_in[1];
    const float* W1 = (const float*)d_in[2];
    const float* b1 = (const float*)d_in[3];
    const float* W2 = (const float*)d_in[4];
    const float* b2 = (const float*)d_in[5];
    float* out = (float*)d_out;

    const int N = in_sizes[0] / 128;
    const int E = in_sizes[1] / 2;
    const int* row = ei;        // sources
    const int* col = ei + E;    // targets

    const int Np = (N + 255) & ~255;
    const int nb = (N + 255) / 256;            // must be <= 512
    const int nbuck = (N + (1 << FB_SHIFT) - 1) >> FB_SHIFT;   // <= 256

    // workspace layout (4-byte units), ~99 MB total
    int*      cnt    = (int*)d_ws;                       // Np
    int*      rowptr = cnt + Np;                         // Np + 256
    int*      cursor = rowptr + Np + 256;                // Np
    int*      bsum   = cursor + Np;                      // 1024
    int*      bcur   = bsum + 1024;                      // 256
    float*    dis    = (float*)(bcur + 256);             // Np
    unsigned* Wt     = (unsigned*)(dis + Np);            // 8192 (W1t bf16)
    int2*     pair   = (int2*)(Wt + 8192);               // E int2
    unsigned* xb     = (unsigned*)(pair + E);            // N*64 (bf16 x)
    unsigned* xab    = xb + (size_t)N * 64;              // N*64 (bf16 A*x)
    unsigned* hb     = xab + (size_t)N * 64;             // N*64 (bf16 h)
    unsigned* zb     = hb + (size_t)N * 64;              // N*20 (bf16 z)
    int2*     bins   = (int2*)xab;    // alias: dead before k_gather1 writes xab

    // degree / norm / CSC build
    hipMemsetAsync(cnt, 0, (size_t)Np * sizeof(int), stream);
    k_count<<<(E + 255) / 256, 256, 0, stream>>>(col, cnt, E);
    k_scan_block<<<nb, 256, 0, stream>>>(cnt, rowptr, bsum, dis, N);
    k_scan_bsum<<<1, 512, 0, stream>>>(bsum, nb);
    k_scan_add<<<nb, 256, 0, stream>>>(rowptr, cursor, bcur, bsum, N, E);
    k_binfill<<<(E + 4095) / 4096, 256, 0, stream>>>(row, col, bcur, bins, E);
    k_fill2<<<nbuck, 256, 0, stream>>>(bins, rowptr, cursor, dis, pair, N, E);

    // conversions
    k_cvt<<<(N * 64 + 255) / 256, 256, 0, stream>>>(x, xb, N * 64);
    k_cvtW<<<32, 256, 0, stream>>>(W1, Wt);

    // layer 1: xab = bf16(A x) ; hb = bf16(relu(xab @ W1 + b1))  [MFMA]
    k_gather1<<<(N + 3) / 4, 256, 0, stream>>>(xb, rowptr, pair, dis, xab, N);
    k_gemm1<<<(N + 127) / 128, 256, 0, stream>>>(xab, Wt, b1, hb, N);

    // layer 2: zb = bf16(h @ W2) ; out = b2 + A z
    k_gemm2<<<(N + 255) / 256, 256, 0, stream>>>(hb, W2, zb, N);
    k_gather2<<<(N + 3) / 4, 256, 0, stream>>>(zb, rowptr, pair, dis, b2, out, N);
}

// Round 9
// 408.032 us; speedup vs baseline: 3.2507x; 1.0607x over previous
//
#include <hip/hip_runtime.h>
#include <hip/hip_bf16.h>

// ---------------------------------------------------------------------------
// 2-layer GCN, atomic-free CSC gather, bf16 payloads + bf16 MFMA GEMM1.
// Layer 1: h = relu((A x) @ W1 + b1)   [reassociated; A = norm adj + self]
// Layer 2: out = A (h @ W2) + b2
// CSC fill: 2-pass LDS multisplit; pass B uses LDS cursors (bucket = 512).
// Gathers: wave-per-node, 8 gathers in flight.
// ---------------------------------------------------------------------------

#define FB_SHIFT 9              // 512 nodes per bucket -> <=256 buckets for N<=131072

__device__ __forceinline__ unsigned bf16rn(float f) {
    unsigned x = __float_as_uint(f);
    unsigned r = ((x >> 16) & 1u) + 0x7fffu;   // RNE
    return (x + r) >> 16;
}
__device__ __forceinline__ float bf_lo(unsigned u) { return __uint_as_float(u << 16); }
__device__ __forceinline__ float bf_hi(unsigned u) { return __uint_as_float(u & 0xffff0000u); }

typedef __bf16 bf16x8 __attribute__((ext_vector_type(8)));
typedef float  f32x4  __attribute__((ext_vector_type(4)));

// ---- degree count ---------------------------------------------------------
__global__ __launch_bounds__(256) void k_count(const int* __restrict__ col,
                                               int* cnt, int E) {
    int e = blockIdx.x * 256 + threadIdx.x;
    if (e < E) atomicAdd(&cnt[col[e]], 1);
}

// ---- block scan of cnt -> rowptr(excl within block) + bsum + dis ----------
__global__ __launch_bounds__(256) void k_scan_block(const int* __restrict__ cnt,
                                                    int* __restrict__ rowptr,
                                                    int* __restrict__ bsum,
                                                    float* __restrict__ dis, int N) {
    __shared__ int s[256];
    int i = blockIdx.x * 256 + threadIdx.x;
    int v = (i < N) ? cnt[i] : 0;
    if (i < N) dis[i] = rsqrtf((float)(v + 1));   // +1 self-loop
    s[threadIdx.x] = v;
    __syncthreads();
#pragma unroll
    for (int off = 1; off < 256; off <<= 1) {
        int t = (threadIdx.x >= off) ? s[threadIdx.x - off] : 0;
        __syncthreads();
        s[threadIdx.x] += t;
        __syncthreads();
    }
    if (i < N) rowptr[i] = s[threadIdx.x] - v;
    if (threadIdx.x == 255) bsum[blockIdx.x] = s[255];
}

__global__ __launch_bounds__(512) void k_scan_bsum(int* bsum, int nb) {
    __shared__ int s[512];
    int t = threadIdx.x;
    int v = (t < nb) ? bsum[t] : 0;
    s[t] = v;
    __syncthreads();
#pragma unroll
    for (int off = 1; off < 512; off <<= 1) {
        int u = (t >= off) ? s[t - off] : 0;
        __syncthreads();
        s[t] += u;
        __syncthreads();
    }
    if (t < nb) bsum[t] = s[t] - v;
}

// finalizes rowptr; initializes per-bucket bin cursor
__global__ __launch_bounds__(256) void k_scan_add(int* __restrict__ rowptr,
                                                  int* __restrict__ bcur,
                                                  const int* __restrict__ bsum,
                                                  int N, int E) {
    int i = blockIdx.x * 256 + threadIdx.x;
    if (i < N) {
        int rp = rowptr[i] + bsum[i >> 8];
        rowptr[i] = rp;
        if ((i & ((1 << FB_SHIFT) - 1)) == 0) bcur[i >> FB_SHIFT] = rp;
    }
    if (i == 0) rowptr[N] = E;
}

// ---- multisplit pass A: bin edges by target bucket (512 nodes/bucket) -----
__global__ __launch_bounds__(256) void k_binfill(const int* __restrict__ row,
                                                 const int* __restrict__ col,
                                                 int* __restrict__ bcur,
                                                 int2* __restrict__ bins, int E) {
    __shared__ int hist[256];
    __shared__ int scn[256];
    __shared__ int gbase[256];
    __shared__ int rcnt[256];
    __shared__ int2 stage[4096];

    const int tid = threadIdx.x;
    const int base = blockIdx.x * 4096;

    hist[tid] = 0;
    rcnt[tid] = 0;
    __syncthreads();

    int2 mye[16];
    int  myb[16];
#pragma unroll
    for (int k = 0; k < 16; ++k) {
        int e = base + k * 256 + tid;
        if (e < E) {
            int r = row[e], c = col[e];
            int b = c >> FB_SHIFT;
            mye[k] = make_int2(r, c);
            myb[k] = b;
            atomicAdd(&hist[b], 1);
        } else {
            myb[k] = -1;
        }
    }
    __syncthreads();

    int v = hist[tid];
    scn[tid] = v;
    __syncthreads();
#pragma unroll
    for (int off = 1; off < 256; off <<= 1) {
        int t = (tid >= off) ? scn[tid - off] : 0;
        __syncthreads();
        scn[tid] += t;
        __syncthreads();
    }
    int excl = scn[tid] - v;
    __syncthreads();
    scn[tid] = excl;
    __syncthreads();

#pragma unroll
    for (int k = 0; k < 16; ++k) {
        int b = myb[k];
        if (b >= 0) {
            int slot = scn[b] + atomicAdd(&rcnt[b], 1);
            stage[slot] = mye[k];
        }
    }

    if (hist[tid] > 0) gbase[tid] = atomicAdd(&bcur[tid], hist[tid]);
    __syncthreads();

    int total = scn[255] + hist[255];
    for (int s = tid; s < total; s += 256) {
        int2 en = stage[s];
        int b = en.y >> FB_SHIFT;
        bins[gbase[b] + (s - scn[b])] = en;
    }
}

// ---- multisplit pass B: bucket-local scatter, LDS cursors -----------------
__global__ __launch_bounds__(256) void k_fill2(const int2* __restrict__ bins,
                                               const int* __restrict__ rowptr,
                                               const float* __restrict__ dis,
                                               int2* __restrict__ pair,
                                               int N, int E) {
    __shared__ int lcur[1 << FB_SHIFT];
    const int b = blockIdx.x;
    const int n0 = b << FB_SHIFT;
    const int n1 = (b + 1) << FB_SHIFT;
    for (int i = threadIdx.x; i < (1 << FB_SHIFT); i += 256) {
        int node = n0 + i;
        lcur[i] = (node < N) ? rowptr[node] : 0;
    }
    __syncthreads();
    int start = rowptr[n0];
    int end = (n1 >= N) ? E : rowptr[n1];
    for (int i = start + threadIdx.x; i < end; i += 256) {
        int2 en = bins[i];
        int r = en.x, c = en.y;
        int pos = atomicAdd(&lcur[c - n0], 1);
        pair[pos] = make_int2(r, __float_as_int(dis[r] * dis[c]));
    }
}

// ---- convert x (fp32) -> xb (bf16x2 packed, 64 uints/row) -----------------
__global__ __launch_bounds__(256) void k_cvt(const float* __restrict__ x,
                                             unsigned* __restrict__ xb, int n64) {
    int i = blockIdx.x * 256 + threadIdx.x;
    if (i >= n64) return;
    float2 v = ((const float2*)x)[i];
    xb[i] = bf16rn(v.x) | (bf16rn(v.y) << 16);
}

// ---- W1 [128k][128n] fp32 -> W1t [n][k] bf16x2-packed (64 uints/row) ------
__global__ __launch_bounds__(256) void k_cvtW(const float* __restrict__ W1,
                                              unsigned* __restrict__ Wt) {
    int t = blockIdx.x * 256 + threadIdx.x;   // 8192 uints
    if (t >= 8192) return;
    int n = t >> 6, kk = (t & 63) * 2;
    unsigned lo = bf16rn(W1[(size_t)kk * 128 + n]);
    unsigned hi = bf16rn(W1[(size_t)(kk + 1) * 128 + n]);
    Wt[t] = lo | (hi << 16);
}

// ---- gather layer 1: xab[v] = bf16(x[v]*dv^2 + sum x[r]*w)  (wave/node) ---
__global__ __launch_bounds__(256) void k_gather1(const unsigned* __restrict__ xb,
                                                 const int* __restrict__ rowptr,
                                                 const int2* __restrict__ pair,
                                                 const float* __restrict__ dis,
                                                 unsigned* __restrict__ xab, int N) {
    int gw = (blockIdx.x * 256 + threadIdx.x) >> 6;
    int lane = threadIdx.x & 63;
    if (gw >= N) return;
    float dv = dis[gw];
    unsigned us = xb[(size_t)gw * 64 + lane];
    float s = dv * dv;
    float2 acc = make_float2(bf_lo(us) * s, bf_hi(us) * s);
    int j = rowptr[gw], je = rowptr[gw + 1];

    for (; j + 7 < je; j += 8) {
        int2 p0 = pair[j],     p1 = pair[j + 1], p2 = pair[j + 2], p3 = pair[j + 3];
        int2 p4 = pair[j + 4], p5 = pair[j + 5], p6 = pair[j + 6], p7 = pair[j + 7];
        unsigned a0 = xb[(size_t)p0.x * 64 + lane];
        unsigned a1 = xb[(size_t)p1.x * 64 + lane];
        unsigned a2 = xb[(size_t)p2.x * 64 + lane];
        unsigned a3 = xb[(size_t)p3.x * 64 + lane];
        unsigned a4 = xb[(size_t)p4.x * 64 + lane];
        unsigned a5 = xb[(size_t)p5.x * 64 + lane];
        unsigned a6 = xb[(size_t)p6.x * 64 + lane];
        unsigned a7 = xb[(size_t)p7.x * 64 + lane];
        float w0 = __int_as_float(p0.y), w1 = __int_as_float(p1.y);
        float w2 = __int_as_float(p2.y), w3 = __int_as_float(p3.y);
        float w4 = __int_as_float(p4.y), w5 = __int_as_float(p5.y);
        float w6 = __int_as_float(p6.y), w7 = __int_as_float(p7.y);
        acc.x += bf_lo(a0) * w0; acc.y += bf_hi(a0) * w0;
        acc.x += bf_lo(a1) * w1; acc.y += bf_hi(a1) * w1;
        acc.x += bf_lo(a2) * w2; acc.y += bf_hi(a2) * w2;
        acc.x += bf_lo(a3) * w3; acc.y += bf_hi(a3) * w3;
        acc.x += bf_lo(a4) * w4; acc.y += bf_hi(a4) * w4;
        acc.x += bf_lo(a5) * w5; acc.y += bf_hi(a5) * w5;
        acc.x += bf_lo(a6) * w6; acc.y += bf_hi(a6) * w6;
        acc.x += bf_lo(a7) * w7; acc.y += bf_hi(a7) * w7;
    }
    for (; j + 3 < je; j += 4) {
        int2 p0 = pair[j], p1 = pair[j + 1], p2 = pair[j + 2], p3 = pair[j + 3];
        unsigned a0 = xb[(size_t)p0.x * 64 + lane];
        unsigned a1 = xb[(size_t)p1.x * 64 + lane];
        unsigned a2 = xb[(size_t)p2.x * 64 + lane];
        unsigned a3 = xb[(size_t)p3.x * 64 + lane];
        float w0 = __int_as_float(p0.y), w1 = __int_as_float(p1.y);
        float w2 = __int_as_float(p2.y), w3 = __int_as_float(p3.y);
        acc.x += bf_lo(a0) * w0; acc.y += bf_hi(a0) * w0;
        acc.x += bf_lo(a1) * w1; acc.y += bf_hi(a1) * w1;
        acc.x += bf_lo(a2) * w2; acc.y += bf_hi(a2) * w2;
        acc.x += bf_lo(a3) * w3; acc.y += bf_hi(a3) * w3;
    }
    for (; j < je; ++j) {
        int2 p0 = pair[j];
        unsigned a0 = xb[(size_t)p0.x * 64 + lane];
        float w0 = __int_as_float(p0.y);
        acc.x += bf_lo(a0) * w0; acc.y += bf_hi(a0) * w0;
    }
    xab[(size_t)gw * 64 + lane] = bf16rn(acc.x) | (bf16rn(acc.y) << 16);
}

// ---- GEMM1 (MFMA bf16): hb[M,128] = bf16(relu(xab @ W1t^T + b1)) ----------
__global__ __launch_bounds__(256) void k_gemm1(const unsigned* __restrict__ Ab,
                                               const unsigned* __restrict__ Wt,
                                               const float* __restrict__ bias,
                                               unsigned* __restrict__ Hb, int M) {
    __shared__ char smem[69632];            // As 128*272 + Bs 128*272
    char* Abase = smem;
    char* Bbase = smem + 34816;

    const int tid = threadIdx.x;
    const int r0 = blockIdx.x * 128;

#pragma unroll
    for (int s = 0; s < 8; ++s) {
        int l = tid + s * 256;
        int row = l >> 4, q = l & 15;
        uint4 va = *(const uint4*)(Ab + (size_t)(r0 + row) * 64 + q * 4);
        *(uint4*)(Abase + row * 272 + q * 16) = va;
        uint4 vb = *(const uint4*)(Wt + (size_t)row * 64 + q * 4);
        *(uint4*)(Bbase + row * 272 + q * 16) = vb;
    }
    __syncthreads();

    const int wv = tid >> 6, lane = tid & 63;
    const int quad = lane >> 4, mcol = lane & 15;

    f32x4 acc[2][8];
#pragma unroll
    for (int rt = 0; rt < 2; ++rt)
#pragma unroll
        for (int ct = 0; ct < 8; ++ct) acc[rt][ct] = (f32x4){0.f, 0.f, 0.f, 0.f};

#pragma unroll
    for (int ks = 0; ks < 4; ++ks) {
        bf16x8 a[2], b[8];
#pragma unroll
        for (int rt = 0; rt < 2; ++rt) {
            int row = wv * 32 + rt * 16 + mcol;
            a[rt] = *(const bf16x8*)(Abase + row * 272 + ks * 64 + quad * 16);
        }
#pragma unroll
        for (int ct = 0; ct < 8; ++ct) {
            int n = ct * 16 + mcol;
            b[ct] = *(const bf16x8*)(Bbase + n * 272 + ks * 64 + quad * 16);
        }
#pragma unroll
        for (int rt = 0; rt < 2; ++rt)
#pragma unroll
            for (int ct = 0; ct < 8; ++ct)
                acc[rt][ct] = __builtin_amdgcn_mfma_f32_16x16x32_bf16(
                    a[rt], b[ct], acc[rt][ct], 0, 0, 0);
    }
    __syncthreads();

    unsigned short* Hs = (unsigned short*)smem;
#pragma unroll
    for (int rt = 0; rt < 2; ++rt)
#pragma unroll
        for (int ct = 0; ct < 8; ++ct) {
            float bb = bias[ct * 16 + mcol];
#pragma unroll
            for (int r = 0; r < 4; ++r) {
                float v = acc[rt][ct][r] + bb;
                v = v > 0.f ? v : 0.f;
                int orow = wv * 32 + rt * 16 + quad * 4 + r;
                Hs[orow * 136 + ct * 16 + mcol] = (unsigned short)bf16rn(v);
            }
        }
    __syncthreads();

    int row = tid >> 1, hf = tid & 1;
    if (r0 + row < M) {
        const uint4* s4 = (const uint4*)(smem + row * 272 + hf * 128);
        uint4* d4 = (uint4*)(Hb + (size_t)(r0 + row) * 64 + hf * 32);
#pragma unroll
        for (int q = 0; q < 8; ++q) d4[q] = s4[q];
    }
}

// ---- GEMM2: Zb[M,40](bf16) = H(bf16)[M,128] @ W2[128,40] ------------------
__global__ __launch_bounds__(256) void k_gemm2(const unsigned* __restrict__ Hb,
                                               const float* __restrict__ W2,
                                               unsigned* __restrict__ Zb, int M) {
    __shared__ float hs[256][33];
    __shared__ float ws2[128][40];

    const int tid = threadIdx.x;
    const int row0 = blockIdx.x * 256;

    for (int idx = tid; idx < 128 * 40; idx += 256) ((float*)ws2)[idx] = W2[idx];

    float4 acc4[10];
#pragma unroll
    for (int j = 0; j < 10; ++j) acc4[j] = make_float4(0.f, 0.f, 0.f, 0.f);

    for (int kt = 0; kt < 4; ++kt) {
        __syncthreads();
#pragma unroll
        for (int s = 0; s < 16; ++s) {
            int l = tid + s * 256;
            int row = l >> 4, q = l & 15;
            int rr = row0 + row;
            unsigned u = (rr < M) ? Hb[(size_t)rr * 64 + kt * 16 + q] : 0u;
            hs[row][2 * q]     = bf_lo(u);
            hs[row][2 * q + 1] = bf_hi(u);
        }
        __syncthreads();
#pragma unroll
        for (int k = 0; k < 32; ++k) {
            float xv = hs[tid][k];
            const float4* wrow = (const float4*)(&ws2[kt * 32 + k][0]);
#pragma unroll
            for (int j4 = 0; j4 < 10; ++j4) {
                float4 b = wrow[j4];
                acc4[j4].x += xv * b.x;
                acc4[j4].y += xv * b.y;
                acc4[j4].z += xv * b.z;
                acc4[j4].w += xv * b.w;
            }
        }
    }

    int rw = row0 + tid;
    if (rw < M) {
        unsigned pk[20];
#pragma unroll
        for (int j4 = 0; j4 < 10; ++j4) {
            pk[j4 * 2]     = bf16rn(acc4[j4].x) | (bf16rn(acc4[j4].y) << 16);
            pk[j4 * 2 + 1] = bf16rn(acc4[j4].z) | (bf16rn(acc4[j4].w) << 16);
        }
        uint4* zp = (uint4*)(&Zb[(size_t)rw * 20]);
#pragma unroll
        for (int q = 0; q < 5; ++q)
            zp[q] = make_uint4(pk[q * 4], pk[q * 4 + 1], pk[q * 4 + 2], pk[q * 4 + 3]);
    }
}

// ---- gather layer 2: out[v] = b2 + z[v]*dv^2 + sum z[r]*w -----------------
// Half-wave per edge stream; 4 edges in flight per half (8/wave).
__global__ __launch_bounds__(256) void k_gather2(const unsigned* __restrict__ zb,
                                                 const int* __restrict__ rowptr,
                                                 const int2* __restrict__ pair,
                                                 const float* __restrict__ dis,
                                                 const float* __restrict__ b2,
                                                 float* __restrict__ out, int N) {
    int gw = (blockIdx.x * 256 + threadIdx.x) >> 6;
    int lane = threadIdx.x & 63;
    if (gw >= N) return;
    int sub = lane >> 5;
    int sl  = lane & 31;
    int f   = (sl < 20) ? sl : 19;

    float2 acc = make_float2(0.f, 0.f);
    float dv = dis[gw];
    if (sub == 0) {
        unsigned u = zb[(size_t)gw * 20 + f];
        float s = dv * dv;
        acc.x = bf_lo(u) * s; acc.y = bf_hi(u) * s;
    }

    int j = rowptr[gw], je = rowptr[gw + 1];
    for (; j + 7 < je; j += 8) {
        int2 pA = pair[j + sub];
        int2 pB = pair[j + 2 + sub];
        int2 pC = pair[j + 4 + sub];
        int2 pD = pair[j + 6 + sub];
        unsigned uA = zb[(size_t)pA.x * 20 + f];
        unsigned uB = zb[(size_t)pB.x * 20 + f];
        unsigned uC = zb[(size_t)pC.x * 20 + f];
        unsigned uD = zb[(size_t)pD.x * 20 + f];
        float wA = __int_as_float(pA.y), wB = __int_as_float(pB.y);
        float wC = __int_as_float(pC.y), wD = __int_as_float(pD.y);
        acc.x += bf_lo(uA) * wA; acc.y += bf_hi(uA) * wA;
        acc.x += bf_lo(uB) * wB; acc.y += bf_hi(uB) * wB;
        acc.x += bf_lo(uC) * wC; acc.y += bf_hi(uC) * wC;
        acc.x += bf_lo(uD) * wD; acc.y += bf_hi(uD) * wD;
    }
    for (; j + 3 < je; j += 4) {
        int2 pA = pair[j + sub];
        int2 pB = pair[j + 2 + sub];
        unsigned uA = zb[(size_t)pA.x * 20 + f];
        unsigned uB = zb[(size_t)pB.x * 20 + f];
        float wA = __int_as_float(pA.y), wB = __int_as_float(pB.y);
        acc.x += bf_lo(uA) * wA; acc.y += bf_hi(uA) * wA;
        acc.x += bf_lo(uB) * wB; acc.y += bf_hi(uB) * wB;
    }
    for (; j + 1 < je; j += 2) {
        int2 p = pair[j + sub];
        unsigned u = zb[(size_t)p.x * 20 + f];
        float w = __int_as_float(p.y);
        acc.x += bf_lo(u) * w; acc.y += bf_hi(u) * w;
    }
    if (j < je && sub == 0) {
        int2 p = pair[j];
        unsigned u = zb[(size_t)p.x * 20 + f];
        float w = __int_as_float(p.y);
        acc.x += bf_lo(u) * w; acc.y += bf_hi(u) * w;
    }

    float bx = __shfl(acc.x, sl + 32, 64);
    float by = __shfl(acc.y, sl + 32, 64);
    if (sub == 0 && sl < 20) {
        float2 bias = ((const float2*)b2)[sl];
        float2 res = make_float2(acc.x + bx + bias.x, acc.y + by + bias.y);
        ((float2*)(out + (size_t)gw * 40))[sl] = res;
    }
}

// ---------------------------------------------------------------------------
extern "C" void kernel_launch(void* const* d_in, const int* in_sizes, int n_in,
                              void* d_out, int out_size, void* d_ws, size_t ws_size,
                              hipStream_t stream) {
    const float* x  = (const float*)d_in[0];
    const int*   ei = (const int*)d_in[1];
    const float* W1 = (const float*)d_in[2];
    const float* b1 = (const float*)d_in[3];
    const float* W2 = (const float*)d_in[4];
    const float* b2 = (const float*)d_in[5];
    float* out = (float*)d_out;

    const int N = in_sizes[0] / 128;
    const int E = in_sizes[1] / 2;
    const int* row = ei;        // sources
    const int* col = ei + E;    // targets

    const int Np = (N + 255) & ~255;
    const int nb = (N + 255) / 256;            // must be <= 512
    const int nbuck = (N + (1 << FB_SHIFT) - 1) >> FB_SHIFT;   // <= 256

    // workspace layout (4-byte units), ~99 MB total
    int*      cnt    = (int*)d_ws;                       // Np
    int*      rowptr = cnt + Np;                         // Np + 256
    int*      bsum   = rowptr + Np + 256;                // 1024
    int*      bcur   = bsum + 1024;                      // 256
    float*    dis    = (float*)(bcur + 256);             // Np
    unsigned* Wt     = (unsigned*)(dis + Np);            // 8192 (W1t bf16)
    int2*     pair   = (int2*)(Wt + 8192);               // E int2
    unsigned* xb     = (unsigned*)(pair + E);            // N*64 (bf16 x)
    unsigned* xab    = xb + (size_t)N * 64;              // N*64 (bf16 A*x)
    unsigned* hb     = xab + (size_t)N * 64;             // N*64 (bf16 h)
    unsigned* zb     = hb + (size_t)N * 64;              // N*20 (bf16 z)
    int2*     bins   = (int2*)xab;    // alias: dead before k_gather1 writes xab

    // degree / norm / CSC build
    hipMemsetAsync(cnt, 0, (size_t)Np * sizeof(int), stream);
    k_count<<<(E + 255) / 256, 256, 0, stream>>>(col, cnt, E);
    k_scan_block<<<nb, 256, 0, stream>>>(cnt, rowptr, bsum, dis, N);
    k_scan_bsum<<<1, 512, 0, stream>>>(bsum, nb);
    k_scan_add<<<nb, 256, 0, stream>>>(rowptr, bcur, bsum, N, E);
    k_binfill<<<(E + 4095) / 4096, 256, 0, stream>>>(row, col, bcur, bins, E);
    k_fill2<<<nbuck, 256, 0, stream>>>(bins, rowptr, dis, pair, N, E);

    // conversions
    k_cvt<<<(N * 64 + 255) / 256, 256, 0, stream>>>(x, xb, N * 64);
    k_cvtW<<<32, 256, 0, stream>>>(W1, Wt);

    // layer 1: xab = bf16(A x) ; hb = bf16(relu(xab @ W1 + b1))  [MFMA]
    k_gather1<<<(N + 3) / 4, 256, 0, stream>>>(xb, rowptr, pair, dis, xab, N);
    k_gemm1<<<(N + 127) / 128, 256, 0, stream>>>(xab, Wt, b1, hb, N);

    // layer 2: zb = bf16(h @ W2) ; out = b2 + A z
    k_gemm2<<<(N + 255) / 256, 256, 0, stream>>>(hb, W2, zb, N);
    k_gather2<<<(N + 3) / 4, 256, 0, stream>>>(zb, rowptr, pair, dis, b2, out, N);
}

// Round 10
// 373.831 us; speedup vs baseline: 3.5481x; 1.0915x over previous
//
#include <hip/hip_runtime.h>
#include <hip/hip_bf16.h>

// ---------------------------------------------------------------------------
// 2-layer GCN, atomic-free CSC gather, bf16 payloads + bf16 MFMA GEMMs.
// Layer 1: h = relu((A x) @ W1 + b1)   [reassociated; A = norm adj + self]
// Layer 2: out = A (h @ W2) + b2
// CSC fill: 2-pass LDS multisplit; pass B uses LDS cursors (bucket = 512).
// Gathers: wave-per-node, 8 gathers in flight. Both GEMMs on MFMA.
// ---------------------------------------------------------------------------

#define FB_SHIFT 9              // 512 nodes per bucket -> <=256 buckets for N<=131072

__device__ __forceinline__ unsigned bf16rn(float f) {
    unsigned x = __float_as_uint(f);
    unsigned r = ((x >> 16) & 1u) + 0x7fffu;   // RNE
    return (x + r) >> 16;
}
__device__ __forceinline__ float bf_lo(unsigned u) { return __uint_as_float(u << 16); }
__device__ __forceinline__ float bf_hi(unsigned u) { return __uint_as_float(u & 0xffff0000u); }

typedef __bf16 bf16x8 __attribute__((ext_vector_type(8)));
typedef float  f32x4  __attribute__((ext_vector_type(4)));

// ---- degree count ---------------------------------------------------------
__global__ __launch_bounds__(256) void k_count(const int* __restrict__ col,
                                               int* cnt, int E) {
    int e = blockIdx.x * 256 + threadIdx.x;
    if (e < E) atomicAdd(&cnt[col[e]], 1);
}

// ---- block scan of cnt -> rowptr(excl within block) + bsum + dis ----------
__global__ __launch_bounds__(256) void k_scan_block(const int* __restrict__ cnt,
                                                    int* __restrict__ rowptr,
                                                    int* __restrict__ bsum,
                                                    float* __restrict__ dis, int N) {
    __shared__ int s[256];
    int i = blockIdx.x * 256 + threadIdx.x;
    int v = (i < N) ? cnt[i] : 0;
    if (i < N) dis[i] = rsqrtf((float)(v + 1));   // +1 self-loop
    s[threadIdx.x] = v;
    __syncthreads();
#pragma unroll
    for (int off = 1; off < 256; off <<= 1) {
        int t = (threadIdx.x >= off) ? s[threadIdx.x - off] : 0;
        __syncthreads();
        s[threadIdx.x] += t;
        __syncthreads();
    }
    if (i < N) rowptr[i] = s[threadIdx.x] - v;
    if (threadIdx.x == 255) bsum[blockIdx.x] = s[255];
}

__global__ __launch_bounds__(512) void k_scan_bsum(int* bsum, int nb) {
    __shared__ int s[512];
    int t = threadIdx.x;
    int v = (t < nb) ? bsum[t] : 0;
    s[t] = v;
    __syncthreads();
#pragma unroll
    for (int off = 1; off < 512; off <<= 1) {
        int u = (t >= off) ? s[t - off] : 0;
        __syncthreads();
        s[t] += u;
        __syncthreads();
    }
    if (t < nb) bsum[t] = s[t] - v;
}

// finalizes rowptr; initializes per-bucket bin cursor
__global__ __launch_bounds__(256) void k_scan_add(int* __restrict__ rowptr,
                                                  int* __restrict__ bcur,
                                                  const int* __restrict__ bsum,
                                                  int N, int E) {
    int i = blockIdx.x * 256 + threadIdx.x;
    if (i < N) {
        int rp = rowptr[i] + bsum[i >> 8];
        rowptr[i] = rp;
        if ((i & ((1 << FB_SHIFT) - 1)) == 0) bcur[i >> FB_SHIFT] = rp;
    }
    if (i == 0) rowptr[N] = E;
}

// ---- multisplit pass A: bin edges by target bucket (512 nodes/bucket) -----
__global__ __launch_bounds__(256) void k_binfill(const int* __restrict__ row,
                                                 const int* __restrict__ col,
                                                 int* __restrict__ bcur,
                                                 int2* __restrict__ bins, int E) {
    __shared__ int hist[256];
    __shared__ int scn[256];
    __shared__ int gbase[256];
    __shared__ int rcnt[256];
    __shared__ int2 stage[4096];

    const int tid = threadIdx.x;
    const int base = blockIdx.x * 4096;

    hist[tid] = 0;
    rcnt[tid] = 0;
    __syncthreads();

    int2 mye[16];
    int  myb[16];
#pragma unroll
    for (int k = 0; k < 16; ++k) {
        int e = base + k * 256 + tid;
        if (e < E) {
            int r = row[e], c = col[e];
            int b = c >> FB_SHIFT;
            mye[k] = make_int2(r, c);
            myb[k] = b;
            atomicAdd(&hist[b], 1);
        } else {
            myb[k] = -1;
        }
    }
    __syncthreads();

    int v = hist[tid];
    scn[tid] = v;
    __syncthreads();
#pragma unroll
    for (int off = 1; off < 256; off <<= 1) {
        int t = (tid >= off) ? scn[tid - off] : 0;
        __syncthreads();
        scn[tid] += t;
        __syncthreads();
    }
    int excl = scn[tid] - v;
    __syncthreads();
    scn[tid] = excl;
    __syncthreads();

#pragma unroll
    for (int k = 0; k < 16; ++k) {
        int b = myb[k];
        if (b >= 0) {
            int slot = scn[b] + atomicAdd(&rcnt[b], 1);
            stage[slot] = mye[k];
        }
    }

    if (hist[tid] > 0) gbase[tid] = atomicAdd(&bcur[tid], hist[tid]);
    __syncthreads();

    int total = scn[255] + hist[255];
    for (int s = tid; s < total; s += 256) {
        int2 en = stage[s];
        int b = en.y >> FB_SHIFT;
        bins[gbase[b] + (s - scn[b])] = en;
    }
}

// ---- multisplit pass B: bucket-local scatter, LDS cursors -----------------
__global__ __launch_bounds__(256) void k_fill2(const int2* __restrict__ bins,
                                               const int* __restrict__ rowptr,
                                               const float* __restrict__ dis,
                                               int2* __restrict__ pair,
                                               int N, int E) {
    __shared__ int lcur[1 << FB_SHIFT];
    const int b = blockIdx.x;
    const int n0 = b << FB_SHIFT;
    const int n1 = (b + 1) << FB_SHIFT;
    for (int i = threadIdx.x; i < (1 << FB_SHIFT); i += 256) {
        int node = n0 + i;
        lcur[i] = (node < N) ? rowptr[node] : 0;
    }
    __syncthreads();
    int start = rowptr[n0];
    int end = (n1 >= N) ? E : rowptr[n1];
    for (int i = start + threadIdx.x; i < end; i += 256) {
        int2 en = bins[i];
        int r = en.x, c = en.y;
        int pos = atomicAdd(&lcur[c - n0], 1);
        pair[pos] = make_int2(r, __float_as_int(dis[r] * dis[c]));
    }
}

// ---- convert x (fp32) -> xb (bf16x2 packed, 64 uints/row) -----------------
__global__ __launch_bounds__(256) void k_cvt(const float* __restrict__ x,
                                             unsigned* __restrict__ xb, int n64) {
    int i = blockIdx.x * 256 + threadIdx.x;
    if (i >= n64) return;
    float2 v = ((const float2*)x)[i];
    xb[i] = bf16rn(v.x) | (bf16rn(v.y) << 16);
}

// ---- W1 [128k][128n] fp32 -> W1t [n][k] bf16x2-packed (64 uints/row) ------
__global__ __launch_bounds__(256) void k_cvtW(const float* __restrict__ W1,
                                              unsigned* __restrict__ Wt) {
    int t = blockIdx.x * 256 + threadIdx.x;   // 8192 uints
    if (t >= 8192) return;
    int n = t >> 6, kk = (t & 63) * 2;
    unsigned lo = bf16rn(W1[(size_t)kk * 128 + n]);
    unsigned hi = bf16rn(W1[(size_t)(kk + 1) * 128 + n]);
    Wt[t] = lo | (hi << 16);
}

// ---- W2 [128k][40n] fp32 -> W2t [48n][k] bf16x2-packed (rows 40-47 = 0) ---
__global__ __launch_bounds__(256) void k_cvtW2(const float* __restrict__ W2,
                                               unsigned* __restrict__ W2t) {
    int t = blockIdx.x * 256 + threadIdx.x;   // 3072 uints
    if (t >= 3072) return;
    int n = t >> 6, kk = (t & 63) * 2;
    unsigned lo = 0, hi = 0;
    if (n < 40) {
        lo = bf16rn(W2[(size_t)kk * 40 + n]);
        hi = bf16rn(W2[(size_t)(kk + 1) * 40 + n]);
    }
    W2t[t] = lo | (hi << 16);
}

// ---- gather layer 1: xab[v] = bf16(x[v]*dv^2 + sum x[r]*w)  (wave/node) ---
__global__ __launch_bounds__(256) void k_gather1(const unsigned* __restrict__ xb,
                                                 const int* __restrict__ rowptr,
                                                 const int2* __restrict__ pair,
                                                 const float* __restrict__ dis,
                                                 unsigned* __restrict__ xab, int N) {
    int gw = (blockIdx.x * 256 + threadIdx.x) >> 6;
    int lane = threadIdx.x & 63;
    if (gw >= N) return;
    float dv = dis[gw];
    unsigned us = xb[(size_t)gw * 64 + lane];
    float s = dv * dv;
    float2 acc = make_float2(bf_lo(us) * s, bf_hi(us) * s);
    int j = rowptr[gw], je = rowptr[gw + 1];

    for (; j + 7 < je; j += 8) {
        int2 p0 = pair[j],     p1 = pair[j + 1], p2 = pair[j + 2], p3 = pair[j + 3];
        int2 p4 = pair[j + 4], p5 = pair[j + 5], p6 = pair[j + 6], p7 = pair[j + 7];
        unsigned a0 = xb[(size_t)p0.x * 64 + lane];
        unsigned a1 = xb[(size_t)p1.x * 64 + lane];
        unsigned a2 = xb[(size_t)p2.x * 64 + lane];
        unsigned a3 = xb[(size_t)p3.x * 64 + lane];
        unsigned a4 = xb[(size_t)p4.x * 64 + lane];
        unsigned a5 = xb[(size_t)p5.x * 64 + lane];
        unsigned a6 = xb[(size_t)p6.x * 64 + lane];
        unsigned a7 = xb[(size_t)p7.x * 64 + lane];
        float w0 = __int_as_float(p0.y), w1 = __int_as_float(p1.y);
        float w2 = __int_as_float(p2.y), w3 = __int_as_float(p3.y);
        float w4 = __int_as_float(p4.y), w5 = __int_as_float(p5.y);
        float w6 = __int_as_float(p6.y), w7 = __int_as_float(p7.y);
        acc.x += bf_lo(a0) * w0; acc.y += bf_hi(a0) * w0;
        acc.x += bf_lo(a1) * w1; acc.y += bf_hi(a1) * w1;
        acc.x += bf_lo(a2) * w2; acc.y += bf_hi(a2) * w2;
        acc.x += bf_lo(a3) * w3; acc.y += bf_hi(a3) * w3;
        acc.x += bf_lo(a4) * w4; acc.y += bf_hi(a4) * w4;
        acc.x += bf_lo(a5) * w5; acc.y += bf_hi(a5) * w5;
        acc.x += bf_lo(a6) * w6; acc.y += bf_hi(a6) * w6;
        acc.x += bf_lo(a7) * w7; acc.y += bf_hi(a7) * w7;
    }
    for (; j + 3 < je; j += 4) {
        int2 p0 = pair[j], p1 = pair[j + 1], p2 = pair[j + 2], p3 = pair[j + 3];
        unsigned a0 = xb[(size_t)p0.x * 64 + lane];
        unsigned a1 = xb[(size_t)p1.x * 64 + lane];
        unsigned a2 = xb[(size_t)p2.x * 64 + lane];
        unsigned a3 = xb[(size_t)p3.x * 64 + lane];
        float w0 = __int_as_float(p0.y), w1 = __int_as_float(p1.y);
        float w2 = __int_as_float(p2.y), w3 = __int_as_float(p3.y);
        acc.x += bf_lo(a0) * w0; acc.y += bf_hi(a0) * w0;
        acc.x += bf_lo(a1) * w1; acc.y += bf_hi(a1) * w1;
        acc.x += bf_lo(a2) * w2; acc.y += bf_hi(a2) * w2;
        acc.x += bf_lo(a3) * w3; acc.y += bf_hi(a3) * w3;
    }
    for (; j < je; ++j) {
        int2 p0 = pair[j];
        unsigned a0 = xb[(size_t)p0.x * 64 + lane];
        float w0 = __int_as_float(p0.y);
        acc.x += bf_lo(a0) * w0; acc.y += bf_hi(a0) * w0;
    }
    xab[(size_t)gw * 64 + lane] = bf16rn(acc.x) | (bf16rn(acc.y) << 16);
}

// ---- GEMM1 (MFMA bf16): hb[M,128] = bf16(relu(xab @ W1t^T + b1)) ----------
__global__ __launch_bounds__(256) void k_gemm1(const unsigned* __restrict__ Ab,
                                               const unsigned* __restrict__ Wt,
                                               const float* __restrict__ bias,
                                               unsigned* __restrict__ Hb, int M) {
    __shared__ char smem[69632];            // As 128*272 + Bs 128*272
    char* Abase = smem;
    char* Bbase = smem + 34816;

    const int tid = threadIdx.x;
    const int r0 = blockIdx.x * 128;

#pragma unroll
    for (int s = 0; s < 8; ++s) {
        int l = tid + s * 256;
        int row = l >> 4, q = l & 15;
        uint4 va = *(const uint4*)(Ab + (size_t)(r0 + row) * 64 + q * 4);
        *(uint4*)(Abase + row * 272 + q * 16) = va;
        uint4 vb = *(const uint4*)(Wt + (size_t)row * 64 + q * 4);
        *(uint4*)(Bbase + row * 272 + q * 16) = vb;
    }
    __syncthreads();

    const int wv = tid >> 6, lane = tid & 63;
    const int quad = lane >> 4, mcol = lane & 15;

    f32x4 acc[2][8];
#pragma unroll
    for (int rt = 0; rt < 2; ++rt)
#pragma unroll
        for (int ct = 0; ct < 8; ++ct) acc[rt][ct] = (f32x4){0.f, 0.f, 0.f, 0.f};

#pragma unroll
    for (int ks = 0; ks < 4; ++ks) {
        bf16x8 a[2], b[8];
#pragma unroll
        for (int rt = 0; rt < 2; ++rt) {
            int row = wv * 32 + rt * 16 + mcol;
            a[rt] = *(const bf16x8*)(Abase + row * 272 + ks * 64 + quad * 16);
        }
#pragma unroll
        for (int ct = 0; ct < 8; ++ct) {
            int n = ct * 16 + mcol;
            b[ct] = *(const bf16x8*)(Bbase + n * 272 + ks * 64 + quad * 16);
        }
#pragma unroll
        for (int rt = 0; rt < 2; ++rt)
#pragma unroll
            for (int ct = 0; ct < 8; ++ct)
                acc[rt][ct] = __builtin_amdgcn_mfma_f32_16x16x32_bf16(
                    a[rt], b[ct], acc[rt][ct], 0, 0, 0);
    }
    __syncthreads();

    unsigned short* Hs = (unsigned short*)smem;
#pragma unroll
    for (int rt = 0; rt < 2; ++rt)
#pragma unroll
        for (int ct = 0; ct < 8; ++ct) {
            float bb = bias[ct * 16 + mcol];
#pragma unroll
            for (int r = 0; r < 4; ++r) {
                float v = acc[rt][ct][r] + bb;
                v = v > 0.f ? v : 0.f;
                int orow = wv * 32 + rt * 16 + quad * 4 + r;
                Hs[orow * 136 + ct * 16 + mcol] = (unsigned short)bf16rn(v);
            }
        }
    __syncthreads();

    int row = tid >> 1, hf = tid & 1;
    if (r0 + row < M) {
        const uint4* s4 = (const uint4*)(smem + row * 272 + hf * 128);
        uint4* d4 = (uint4*)(Hb + (size_t)(r0 + row) * 64 + hf * 32);
#pragma unroll
        for (int q = 0; q < 8; ++q) d4[q] = s4[q];
    }
}

// ---- GEMM2 (MFMA bf16): Zb[M,40](bf16) = hb[M,128] @ W2t^T ----------------
// 128 rows x 48 cols (40 real), K=128 staged once. Same LDS pitch as gemm1.
__global__ __launch_bounds__(256) void k_gemm2(const unsigned* __restrict__ Hb,
                                               const unsigned* __restrict__ W2t,
                                               unsigned* __restrict__ Zb, int M) {
    __shared__ char smem[47872];            // As 128*272 + Bs 48*272
    char* Abase = smem;
    char* Bbase = smem + 34816;

    const int tid = threadIdx.x;
    const int r0 = blockIdx.x * 128;

    // stage A: 2048 uint4 (8/thread); rows beyond M read in-bounds scratch
#pragma unroll
    for (int s = 0; s < 8; ++s) {
        int l = tid + s * 256;
        int row = l >> 4, q = l & 15;
        uint4 va = *(const uint4*)(Hb + (size_t)(r0 + row) * 64 + q * 4);
        *(uint4*)(Abase + row * 272 + q * 16) = va;
    }
    // stage B: 768 uint4 (3/thread)
#pragma unroll
    for (int s = 0; s < 3; ++s) {
        int l = tid + s * 256;
        int row = l >> 4, q = l & 15;
        uint4 vb = *(const uint4*)(W2t + (size_t)row * 64 + q * 4);
        *(uint4*)(Bbase + row * 272 + q * 16) = vb;
    }
    __syncthreads();

    const int wv = tid >> 6, lane = tid & 63;
    const int quad = lane >> 4, mcol = lane & 15;

    f32x4 acc[2][3];
#pragma unroll
    for (int rt = 0; rt < 2; ++rt)
#pragma unroll
        for (int ct = 0; ct < 3; ++ct) acc[rt][ct] = (f32x4){0.f, 0.f, 0.f, 0.f};

#pragma unroll
    for (int ks = 0; ks < 4; ++ks) {
        bf16x8 a[2], b[3];
#pragma unroll
        for (int rt = 0; rt < 2; ++rt) {
            int row = wv * 32 + rt * 16 + mcol;
            a[rt] = *(const bf16x8*)(Abase + row * 272 + ks * 64 + quad * 16);
        }
#pragma unroll
        for (int ct = 0; ct < 3; ++ct) {
            int n = ct * 16 + mcol;
            b[ct] = *(const bf16x8*)(Bbase + n * 272 + ks * 64 + quad * 16);
        }
#pragma unroll
        for (int rt = 0; rt < 2; ++rt)
#pragma unroll
            for (int ct = 0; ct < 3; ++ct)
                acc[rt][ct] = __builtin_amdgcn_mfma_f32_16x16x32_bf16(
                    a[rt], b[ct], acc[rt][ct], 0, 0, 0);
    }
    __syncthreads();

    // epilogue: pack bf16 rows (48 cols, 40 valid) at 56-ushort pitch (112 B)
    unsigned short* Hs = (unsigned short*)smem;
#pragma unroll
    for (int rt = 0; rt < 2; ++rt)
#pragma unroll
        for (int ct = 0; ct < 3; ++ct) {
#pragma unroll
            for (int r = 0; r < 4; ++r) {
                int orow = wv * 32 + rt * 16 + quad * 4 + r;
                Hs[orow * 56 + ct * 16 + mcol] =
                    (unsigned short)bf16rn(acc[rt][ct][r]);
            }
        }
    __syncthreads();

    if (tid < 128) {
        int rr = r0 + tid;
        if (rr < M) {
            const uint4* s4 = (const uint4*)(smem + tid * 112);
            uint4* d4 = (uint4*)(Zb + (size_t)rr * 20);
#pragma unroll
            for (int q = 0; q < 5; ++q) d4[q] = s4[q];
        }
    }
}

// ---- gather layer 2: out[v] = b2 + z[v]*dv^2 + sum z[r]*w -----------------
// Half-wave per edge stream; 4 edges in flight per half (8/wave).
__global__ __launch_bounds__(256) void k_gather2(const unsigned* __restrict__ zb,
                                                 const int* __restrict__ rowptr,
                                                 const int2* __restrict__ pair,
                                                 const float* __restrict__ dis,
                                                 const float* __restrict__ b2,
                                                 float* __restrict__ out, int N) {
    int gw = (blockIdx.x * 256 + threadIdx.x) >> 6;
    int lane = threadIdx.x & 63;
    if (gw >= N) return;
    int sub = lane >> 5;
    int sl  = lane & 31;
    int f   = (sl < 20) ? sl : 19;

    float2 acc = make_float2(0.f, 0.f);
    float dv = dis[gw];
    if (sub == 0) {
        unsigned u = zb[(size_t)gw * 20 + f];
        float s = dv * dv;
        acc.x = bf_lo(u) * s; acc.y = bf_hi(u) * s;
    }

    int j = rowptr[gw], je = rowptr[gw + 1];
    for (; j + 7 < je; j += 8) {
        int2 pA = pair[j + sub];
        int2 pB = pair[j + 2 + sub];
        int2 pC = pair[j + 4 + sub];
        int2 pD = pair[j + 6 + sub];
        unsigned uA = zb[(size_t)pA.x * 20 + f];
        unsigned uB = zb[(size_t)pB.x * 20 + f];
        unsigned uC = zb[(size_t)pC.x * 20 + f];
        unsigned uD = zb[(size_t)pD.x * 20 + f];
        float wA = __int_as_float(pA.y), wB = __int_as_float(pB.y);
        float wC = __int_as_float(pC.y), wD = __int_as_float(pD.y);
        acc.x += bf_lo(uA) * wA; acc.y += bf_hi(uA) * wA;
        acc.x += bf_lo(uB) * wB; acc.y += bf_hi(uB) * wB;
        acc.x += bf_lo(uC) * wC; acc.y += bf_hi(uC) * wC;
        acc.x += bf_lo(uD) * wD; acc.y += bf_hi(uD) * wD;
    }
    for (; j + 3 < je; j += 4) {
        int2 pA = pair[j + sub];
        int2 pB = pair[j + 2 + sub];
        unsigned uA = zb[(size_t)pA.x * 20 + f];
        unsigned uB = zb[(size_t)pB.x * 20 + f];
        float wA = __int_as_float(pA.y), wB = __int_as_float(pB.y);
        acc.x += bf_lo(uA) * wA; acc.y += bf_hi(uA) * wA;
        acc.x += bf_lo(uB) * wB; acc.y += bf_hi(uB) * wB;
    }
    for (; j + 1 < je; j += 2) {
        int2 p = pair[j + sub];
        unsigned u = zb[(size_t)p.x * 20 + f];
        float w = __int_as_float(p.y);
        acc.x += bf_lo(u) * w; acc.y += bf_hi(u) * w;
    }
    if (j < je && sub == 0) {
        int2 p = pair[j];
        unsigned u = zb[(size_t)p.x * 20 + f];
        float w = __int_as_float(p.y);
        acc.x += bf_lo(u) * w; acc.y += bf_hi(u) * w;
    }

    float bx = __shfl(acc.x, sl + 32, 64);
    float by = __shfl(acc.y, sl + 32, 64);
    if (sub == 0 && sl < 20) {
        float2 bias = ((const float2*)b2)[sl];
        float2 res = make_float2(acc.x + bx + bias.x, acc.y + by + bias.y);
        ((float2*)(out + (size_t)gw * 40))[sl] = res;
    }
}

// ---------------------------------------------------------------------------
extern "C" void kernel_launch(void* const* d_in, const int* in_sizes, int n_in,
                              void* d_out, int out_size, void* d_ws, size_t ws_size,
                              hipStream_t stream) {
    const float* x  = (const float*)d_in[0];
    const int*   ei = (const int*)d_in[1];
    const float* W1 = (const float*)d_in[2];
    const float* b1 = (const float*)d_in[3];
    const float* W2 = (const float*)d_in[4];
    const float* b2 = (const float*)d_in[5];
    float* out = (float*)d_out;

    const int N = in_sizes[0] / 128;
    const int E = in_sizes[1] / 2;
    const int* row = ei;        // sources
    const int* col = ei + E;    // targets

    const int Np = (N + 255) & ~255;
    const int nb = (N + 255) / 256;            // must be <= 512
    const int nbuck = (N + (1 << FB_SHIFT) - 1) >> FB_SHIFT;   // <= 256

    // workspace layout (4-byte units), ~99 MB total
    int*      cnt    = (int*)d_ws;                       // Np
    int*      rowptr = cnt + Np;                         // Np + 256
    int*      bsum   = rowptr + Np + 256;                // 1024
    int*      bcur   = bsum + 1024;                      // 256
    float*    dis    = (float*)(bcur + 256);             // Np
    unsigned* Wt     = (unsigned*)(dis + Np);            // 8192 (W1t bf16)
    unsigned* W2t    = Wt + 8192;                        // 3072 (W2t bf16, 48 rows)
    int2*     pair   = (int2*)(W2t + 3072);              // E int2
    unsigned* xb     = (unsigned*)(pair + E);            // N*64 (bf16 x)
    unsigned* xab    = xb + (size_t)N * 64;              // N*64 (bf16 A*x)
    unsigned* hb     = xab + (size_t)N * 64;             // N*64 (bf16 h)
    unsigned* zb     = hb + (size_t)N * 64;              // N*20 (bf16 z)
    int2*     bins   = (int2*)xab;    // alias: dead before k_gather1 writes xab

    // degree / norm / CSC build
    hipMemsetAsync(cnt, 0, (size_t)Np * sizeof(int), stream);
    k_count<<<(E + 255) / 256, 256, 0, stream>>>(col, cnt, E);
    k_scan_block<<<nb, 256, 0, stream>>>(cnt, rowptr, bsum, dis, N);
    k_scan_bsum<<<1, 512, 0, stream>>>(bsum, nb);
    k_scan_add<<<nb, 256, 0, stream>>>(rowptr, bcur, bsum, N, E);
    k_binfill<<<(E + 4095) / 4096, 256, 0, stream>>>(row, col, bcur, bins, E);
    k_fill2<<<nbuck, 256, 0, stream>>>(bins, rowptr, dis, pair, N, E);

    // conversions
    k_cvt<<<(N * 64 + 255) / 256, 256, 0, stream>>>(x, xb, N * 64);
    k_cvtW<<<32, 256, 0, stream>>>(W1, Wt);
    k_cvtW2<<<12, 256, 0, stream>>>(W2, W2t);

    // layer 1: xab = bf16(A x) ; hb = bf16(relu(xab @ W1 + b1))  [MFMA]
    k_gather1<<<(N + 3) / 4, 256, 0, stream>>>(xb, rowptr, pair, dis, xab, N);
    k_gemm1<<<(N + 127) / 128, 256, 0, stream>>>(xab, Wt, b1, hb, N);

    // layer 2: zb = bf16(h @ W2) [MFMA] ; out = b2 + A z
    k_gemm2<<<(N + 127) / 128, 256, 0, stream>>>(hb, W2t, zb, N);
    k_gather2<<<(N + 3) / 4, 256, 0, stream>>>(zb, rowptr, pair, dis, b2, out, N);
}

// Round 11
// 362.316 us; speedup vs baseline: 3.6609x; 1.0318x over previous
//
#include <hip/hip_runtime.h>
#include <hip/hip_bf16.h>

// ---------------------------------------------------------------------------
// 2-layer GCN, atomic-free CSC gather, bf16 payloads + bf16 MFMA GEMMs.
// dis[] is folded into the gathered payloads (xb = x*dis, zb = z*dis), so
// edge records are source-index-only (4 B). Aggregation at target c:
//   A·v|_c = dis[c] * (sum_r payload[r] + payload[c])
// Layer 1: h = relu((A x) @ W1 + b1)   [reassociated]
// Layer 2: out = A (h @ W2) + b2
// ---------------------------------------------------------------------------

#define FB_SHIFT 9              // 512 nodes per bucket; r<2^17 packs with c_local

__device__ __forceinline__ unsigned bf16rn(float f) {
    unsigned x = __float_as_uint(f);
    unsigned r = ((x >> 16) & 1u) + 0x7fffu;   // RNE
    return (x + r) >> 16;
}
__device__ __forceinline__ float bf_lo(unsigned u) { return __uint_as_float(u << 16); }
__device__ __forceinline__ float bf_hi(unsigned u) { return __uint_as_float(u & 0xffff0000u); }

typedef __bf16 bf16x8 __attribute__((ext_vector_type(8)));
typedef float  f32x4  __attribute__((ext_vector_type(4)));

// ---- degree count ---------------------------------------------------------
__global__ __launch_bounds__(256) void k_count(const int* __restrict__ col,
                                               int* cnt, int E) {
    int e = blockIdx.x * 256 + threadIdx.x;
    if (e < E) atomicAdd(&cnt[col[e]], 1);
}

// ---- block scan of cnt -> rowptr(excl within block) + bsum + dis ----------
__global__ __launch_bounds__(256) void k_scan_block(const int* __restrict__ cnt,
                                                    int* __restrict__ rowptr,
                                                    int* __restrict__ bsum,
                                                    float* __restrict__ dis, int N) {
    __shared__ int s[256];
    int i = blockIdx.x * 256 + threadIdx.x;
    int v = (i < N) ? cnt[i] : 0;
    if (i < N) dis[i] = rsqrtf((float)(v + 1));   // +1 self-loop
    s[threadIdx.x] = v;
    __syncthreads();
#pragma unroll
    for (int off = 1; off < 256; off <<= 1) {
        int t = (threadIdx.x >= off) ? s[threadIdx.x - off] : 0;
        __syncthreads();
        s[threadIdx.x] += t;
        __syncthreads();
    }
    if (i < N) rowptr[i] = s[threadIdx.x] - v;
    if (threadIdx.x == 255) bsum[blockIdx.x] = s[255];
}

__global__ __launch_bounds__(512) void k_scan_bsum(int* bsum, int nb) {
    __shared__ int s[512];
    int t = threadIdx.x;
    int v = (t < nb) ? bsum[t] : 0;
    s[t] = v;
    __syncthreads();
#pragma unroll
    for (int off = 1; off < 512; off <<= 1) {
        int u = (t >= off) ? s[t - off] : 0;
        __syncthreads();
        s[t] += u;
        __syncthreads();
    }
    if (t < nb) bsum[t] = s[t] - v;
}

// finalizes rowptr; initializes per-bucket bin cursor
__global__ __launch_bounds__(256) void k_scan_add(int* __restrict__ rowptr,
                                                  int* __restrict__ bcur,
                                                  const int* __restrict__ bsum,
                                                  int N, int E) {
    int i = blockIdx.x * 256 + threadIdx.x;
    if (i < N) {
        int rp = rowptr[i] + bsum[i >> 8];
        rowptr[i] = rp;
        if ((i & ((1 << FB_SHIFT) - 1)) == 0) bcur[i >> FB_SHIFT] = rp;
    }
    if (i == 0) rowptr[N] = E;
}

// ---- multisplit pass A: bin edges by target bucket, packed (r<<9|c_local) -
__global__ __launch_bounds__(256) void k_binfill(const int* __restrict__ row,
                                                 const int* __restrict__ col,
                                                 int* __restrict__ bcur,
                                                 unsigned* __restrict__ bins, int E) {
    __shared__ int hist[256];
    __shared__ int scn[256];
    __shared__ int gbase[256];
    __shared__ int rcnt[256];
    __shared__ unsigned stage[4096];
    __shared__ unsigned char bkts[4096];

    const int tid = threadIdx.x;
    const int base = blockIdx.x * 4096;

    hist[tid] = 0;
    rcnt[tid] = 0;
    __syncthreads();

    unsigned mypk[16];
    int      myb[16];
#pragma unroll
    for (int k = 0; k < 16; ++k) {
        int e = base + k * 256 + tid;
        if (e < E) {
            int r = row[e], c = col[e];
            int b = c >> FB_SHIFT;
            mypk[k] = ((unsigned)r << FB_SHIFT) | (unsigned)(c & ((1 << FB_SHIFT) - 1));
            myb[k] = b;
            atomicAdd(&hist[b], 1);
        } else {
            myb[k] = -1;
        }
    }
    __syncthreads();

    int v = hist[tid];
    scn[tid] = v;
    __syncthreads();
#pragma unroll
    for (int off = 1; off < 256; off <<= 1) {
        int t = (tid >= off) ? scn[tid - off] : 0;
        __syncthreads();
        scn[tid] += t;
        __syncthreads();
    }
    int excl = scn[tid] - v;
    __syncthreads();
    scn[tid] = excl;
    __syncthreads();

#pragma unroll
    for (int k = 0; k < 16; ++k) {
        int b = myb[k];
        if (b >= 0) {
            int slot = scn[b] + atomicAdd(&rcnt[b], 1);
            stage[slot] = mypk[k];
            bkts[slot] = (unsigned char)b;
        }
    }

    if (hist[tid] > 0) gbase[tid] = atomicAdd(&bcur[tid], hist[tid]);
    __syncthreads();

    int total = scn[255] + hist[255];
    for (int s = tid; s < total; s += 256) {
        unsigned u = stage[s];
        int b = bkts[s];
        bins[gbase[b] + (s - scn[b])] = u;
    }
}

// ---- multisplit pass B: bucket-local scatter, LDS cursors, index-only -----
__global__ __launch_bounds__(256) void k_fill2(const unsigned* __restrict__ bins,
                                               const int* __restrict__ rowptr,
                                               int* __restrict__ pair,
                                               int N, int E) {
    __shared__ int lcur[1 << FB_SHIFT];
    const int b = blockIdx.x;
    const int n0 = b << FB_SHIFT;
    const int n1 = (b + 1) << FB_SHIFT;
    for (int i = threadIdx.x; i < (1 << FB_SHIFT); i += 256) {
        int node = n0 + i;
        lcur[i] = (node < N) ? rowptr[node] : 0;
    }
    __syncthreads();
    int start = rowptr[n0];
    int end = (n1 >= N) ? E : rowptr[n1];
    for (int i = start + threadIdx.x; i < end; i += 256) {
        unsigned u = bins[i];
        int cl = (int)(u & ((1 << FB_SHIFT) - 1));
        int pos = atomicAdd(&lcur[cl], 1);
        pair[pos] = (int)(u >> FB_SHIFT);
    }
}

// ---- convert x -> xb = bf16x2(x * dis), 64 uints/row ----------------------
__global__ __launch_bounds__(256) void k_cvt(const float* __restrict__ x,
                                             const float* __restrict__ dis,
                                             unsigned* __restrict__ xb, int n64) {
    int i = blockIdx.x * 256 + threadIdx.x;
    if (i >= n64) return;
    float2 v = ((const float2*)x)[i];
    float d = dis[i >> 6];
    xb[i] = bf16rn(v.x * d) | (bf16rn(v.y * d) << 16);
}

// ---- W1 [128k][128n] fp32 -> W1t [n][k] bf16x2-packed (64 uints/row) ------
__global__ __launch_bounds__(256) void k_cvtW(const float* __restrict__ W1,
                                              unsigned* __restrict__ Wt) {
    int t = blockIdx.x * 256 + threadIdx.x;   // 8192 uints
    if (t >= 8192) return;
    int n = t >> 6, kk = (t & 63) * 2;
    unsigned lo = bf16rn(W1[(size_t)kk * 128 + n]);
    unsigned hi = bf16rn(W1[(size_t)(kk + 1) * 128 + n]);
    Wt[t] = lo | (hi << 16);
}

// ---- W2 [128k][40n] fp32 -> W2t [48n][k] bf16x2-packed (rows 40-47 = 0) ---
__global__ __launch_bounds__(256) void k_cvtW2(const float* __restrict__ W2,
                                               unsigned* __restrict__ W2t) {
    int t = blockIdx.x * 256 + threadIdx.x;   // 3072 uints
    if (t >= 3072) return;
    int n = t >> 6, kk = (t & 63) * 2;
    unsigned lo = 0, hi = 0;
    if (n < 40) {
        lo = bf16rn(W2[(size_t)kk * 40 + n]);
        hi = bf16rn(W2[(size_t)(kk + 1) * 40 + n]);
    }
    W2t[t] = lo | (hi << 16);
}

// ---- gather layer 1: xab[c] = bf16(dis[c] * (sum_r xb[r] + xb[c])) --------
// Wave per node; index-only pair records; 8 gathers in flight.
__global__ __launch_bounds__(256) void k_gather1(const unsigned* __restrict__ xb,
                                                 const int* __restrict__ rowptr,
                                                 const int* __restrict__ pair,
                                                 const float* __restrict__ dis,
                                                 unsigned* __restrict__ xab, int N) {
    int gw = (blockIdx.x * 256 + threadIdx.x) >> 6;
    int lane = threadIdx.x & 63;
    if (gw >= N) return;
    float dv = dis[gw];
    unsigned us = xb[(size_t)gw * 64 + lane];
    float2 acc = make_float2(bf_lo(us), bf_hi(us));   // self term (rows pre-scaled)
    int j = rowptr[gw], je = rowptr[gw + 1];

    for (; j + 7 < je; j += 8) {
        int r0 = pair[j],     r1 = pair[j + 1], r2 = pair[j + 2], r3 = pair[j + 3];
        int r4 = pair[j + 4], r5 = pair[j + 5], r6 = pair[j + 6], r7 = pair[j + 7];
        unsigned a0 = xb[(size_t)r0 * 64 + lane];
        unsigned a1 = xb[(size_t)r1 * 64 + lane];
        unsigned a2 = xb[(size_t)r2 * 64 + lane];
        unsigned a3 = xb[(size_t)r3 * 64 + lane];
        unsigned a4 = xb[(size_t)r4 * 64 + lane];
        unsigned a5 = xb[(size_t)r5 * 64 + lane];
        unsigned a6 = xb[(size_t)r6 * 64 + lane];
        unsigned a7 = xb[(size_t)r7 * 64 + lane];
        acc.x += bf_lo(a0); acc.y += bf_hi(a0);
        acc.x += bf_lo(a1); acc.y += bf_hi(a1);
        acc.x += bf_lo(a2); acc.y += bf_hi(a2);
        acc.x += bf_lo(a3); acc.y += bf_hi(a3);
        acc.x += bf_lo(a4); acc.y += bf_hi(a4);
        acc.x += bf_lo(a5); acc.y += bf_hi(a5);
        acc.x += bf_lo(a6); acc.y += bf_hi(a6);
        acc.x += bf_lo(a7); acc.y += bf_hi(a7);
    }
    for (; j + 3 < je; j += 4) {
        int r0 = pair[j], r1 = pair[j + 1], r2 = pair[j + 2], r3 = pair[j + 3];
        unsigned a0 = xb[(size_t)r0 * 64 + lane];
        unsigned a1 = xb[(size_t)r1 * 64 + lane];
        unsigned a2 = xb[(size_t)r2 * 64 + lane];
        unsigned a3 = xb[(size_t)r3 * 64 + lane];
        acc.x += bf_lo(a0); acc.y += bf_hi(a0);
        acc.x += bf_lo(a1); acc.y += bf_hi(a1);
        acc.x += bf_lo(a2); acc.y += bf_hi(a2);
        acc.x += bf_lo(a3); acc.y += bf_hi(a3);
    }
    for (; j < je; ++j) {
        unsigned a0 = xb[(size_t)pair[j] * 64 + lane];
        acc.x += bf_lo(a0); acc.y += bf_hi(a0);
    }
    xab[(size_t)gw * 64 + lane] = bf16rn(dv * acc.x) | (bf16rn(dv * acc.y) << 16);
}

// ---- GEMM1 (MFMA bf16): hb[M,128] = bf16(relu(xab @ W1t^T + b1)) ----------
__global__ __launch_bounds__(256) void k_gemm1(const unsigned* __restrict__ Ab,
                                               const unsigned* __restrict__ Wt,
                                               const float* __restrict__ bias,
                                               unsigned* __restrict__ Hb, int M) {
    __shared__ char smem[69632];            // As 128*272 + Bs 128*272
    char* Abase = smem;
    char* Bbase = smem + 34816;

    const int tid = threadIdx.x;
    const int r0 = blockIdx.x * 128;

#pragma unroll
    for (int s = 0; s < 8; ++s) {
        int l = tid + s * 256;
        int row = l >> 4, q = l & 15;
        uint4 va = *(const uint4*)(Ab + (size_t)(r0 + row) * 64 + q * 4);
        *(uint4*)(Abase + row * 272 + q * 16) = va;
        uint4 vb = *(const uint4*)(Wt + (size_t)row * 64 + q * 4);
        *(uint4*)(Bbase + row * 272 + q * 16) = vb;
    }
    __syncthreads();

    const int wv = tid >> 6, lane = tid & 63;
    const int quad = lane >> 4, mcol = lane & 15;

    f32x4 acc[2][8];
#pragma unroll
    for (int rt = 0; rt < 2; ++rt)
#pragma unroll
        for (int ct = 0; ct < 8; ++ct) acc[rt][ct] = (f32x4){0.f, 0.f, 0.f, 0.f};

#pragma unroll
    for (int ks = 0; ks < 4; ++ks) {
        bf16x8 a[2], b[8];
#pragma unroll
        for (int rt = 0; rt < 2; ++rt) {
            int row = wv * 32 + rt * 16 + mcol;
            a[rt] = *(const bf16x8*)(Abase + row * 272 + ks * 64 + quad * 16);
        }
#pragma unroll
        for (int ct = 0; ct < 8; ++ct) {
            int n = ct * 16 + mcol;
            b[ct] = *(const bf16x8*)(Bbase + n * 272 + ks * 64 + quad * 16);
        }
#pragma unroll
        for (int rt = 0; rt < 2; ++rt)
#pragma unroll
            for (int ct = 0; ct < 8; ++ct)
                acc[rt][ct] = __builtin_amdgcn_mfma_f32_16x16x32_bf16(
                    a[rt], b[ct], acc[rt][ct], 0, 0, 0);
    }
    __syncthreads();

    unsigned short* Hs = (unsigned short*)smem;
#pragma unroll
    for (int rt = 0; rt < 2; ++rt)
#pragma unroll
        for (int ct = 0; ct < 8; ++ct) {
            float bb = bias[ct * 16 + mcol];
#pragma unroll
            for (int r = 0; r < 4; ++r) {
                float v = acc[rt][ct][r] + bb;
                v = v > 0.f ? v : 0.f;
                int orow = wv * 32 + rt * 16 + quad * 4 + r;
                Hs[orow * 136 + ct * 16 + mcol] = (unsigned short)bf16rn(v);
            }
        }
    __syncthreads();

    int row = tid >> 1, hf = tid & 1;
    if (r0 + row < M) {
        const uint4* s4 = (const uint4*)(smem + row * 272 + hf * 128);
        uint4* d4 = (uint4*)(Hb + (size_t)(r0 + row) * 64 + hf * 32);
#pragma unroll
        for (int q = 0; q < 8; ++q) d4[q] = s4[q];
    }
}

// ---- GEMM2 (MFMA bf16): Zb[M,40] = bf16( (hb @ W2t^T) * dis[row] ) --------
// 128 rows x 48 cols (40 real), K=128 staged once; dis folded in epilogue.
__global__ __launch_bounds__(256) void k_gemm2(const unsigned* __restrict__ Hb,
                                               const unsigned* __restrict__ W2t,
                                               const float* __restrict__ dis,
                                               unsigned* __restrict__ Zb, int M) {
    __shared__ char smem[47872];            // As 128*272 + Bs 48*272
    __shared__ float ldis[128];
    char* Abase = smem;
    char* Bbase = smem + 34816;

    const int tid = threadIdx.x;
    const int r0 = blockIdx.x * 128;

#pragma unroll
    for (int s = 0; s < 8; ++s) {
        int l = tid + s * 256;
        int row = l >> 4, q = l & 15;
        uint4 va = *(const uint4*)(Hb + (size_t)(r0 + row) * 64 + q * 4);
        *(uint4*)(Abase + row * 272 + q * 16) = va;
    }
#pragma unroll
    for (int s = 0; s < 3; ++s) {
        int l = tid + s * 256;
        int row = l >> 4, q = l & 15;
        uint4 vb = *(const uint4*)(W2t + (size_t)row * 64 + q * 4);
        *(uint4*)(Bbase + row * 272 + q * 16) = vb;
    }
    if (tid < 128) {
        int rr = r0 + tid;
        ldis[tid] = (rr < M) ? dis[rr] : 0.f;
    }
    __syncthreads();

    const int wv = tid >> 6, lane = tid & 63;
    const int quad = lane >> 4, mcol = lane & 15;

    f32x4 acc[2][3];
#pragma unroll
    for (int rt = 0; rt < 2; ++rt)
#pragma unroll
        for (int ct = 0; ct < 3; ++ct) acc[rt][ct] = (f32x4){0.f, 0.f, 0.f, 0.f};

#pragma unroll
    for (int ks = 0; ks < 4; ++ks) {
        bf16x8 a[2], b[3];
#pragma unroll
        for (int rt = 0; rt < 2; ++rt) {
            int row = wv * 32 + rt * 16 + mcol;
            a[rt] = *(const bf16x8*)(Abase + row * 272 + ks * 64 + quad * 16);
        }
#pragma unroll
        for (int ct = 0; ct < 3; ++ct) {
            int n = ct * 16 + mcol;
            b[ct] = *(const bf16x8*)(Bbase + n * 272 + ks * 64 + quad * 16);
        }
#pragma unroll
        for (int rt = 0; rt < 2; ++rt)
#pragma unroll
            for (int ct = 0; ct < 3; ++ct)
                acc[rt][ct] = __builtin_amdgcn_mfma_f32_16x16x32_bf16(
                    a[rt], b[ct], acc[rt][ct], 0, 0, 0);
    }
    __syncthreads();

    // epilogue: scale by dis[row], pack bf16 rows at 56-ushort pitch (112 B)
    unsigned short* Hs = (unsigned short*)smem;
#pragma unroll
    for (int rt = 0; rt < 2; ++rt)
#pragma unroll
        for (int ct = 0; ct < 3; ++ct) {
#pragma unroll
            for (int r = 0; r < 4; ++r) {
                int orow = wv * 32 + rt * 16 + quad * 4 + r;
                float v = acc[rt][ct][r] * ldis[orow];
                Hs[orow * 56 + ct * 16 + mcol] = (unsigned short)bf16rn(v);
            }
        }
    __syncthreads();

    if (tid < 128) {
        int rr = r0 + tid;
        if (rr < M) {
            const uint4* s4 = (const uint4*)(smem + tid * 112);
            uint4* d4 = (uint4*)(Zb + (size_t)rr * 20);
#pragma unroll
            for (int q = 0; q < 5; ++q) d4[q] = s4[q];
        }
    }
}

// ---- gather layer 2: out[c] = b2 + dis[c] * (sum_r zb[r] + zb[c]) ---------
// Half-wave per edge stream; index-only records; 4 edges in flight per half.
__global__ __launch_bounds__(256) void k_gather2(const unsigned* __restrict__ zb,
                                                 const int* __restrict__ rowptr,
                                                 const int* __restrict__ pair,
                                                 const float* __restrict__ dis,
                                                 const float* __restrict__ b2,
                                                 float* __restrict__ out, int N) {
    int gw = (blockIdx.x * 256 + threadIdx.x) >> 6;
    int lane = threadIdx.x & 63;
    if (gw >= N) return;
    int sub = lane >> 5;
    int sl  = lane & 31;
    int f   = (sl < 20) ? sl : 19;

    float2 acc = make_float2(0.f, 0.f);
    float dv = dis[gw];
    if (sub == 0) {                       // self term (rows pre-scaled by dis)
        unsigned u = zb[(size_t)gw * 20 + f];
        acc.x = bf_lo(u); acc.y = bf_hi(u);
    }

    int j = rowptr[gw], je = rowptr[gw + 1];
    for (; j + 7 < je; j += 8) {
        int rA = pair[j + sub];
        int rB = pair[j + 2 + sub];
        int rC = pair[j + 4 + sub];
        int rD = pair[j + 6 + sub];
        unsigned uA = zb[(size_t)rA * 20 + f];
        unsigned uB = zb[(size_t)rB * 20 + f];
        unsigned uC = zb[(size_t)rC * 20 + f];
        unsigned uD = zb[(size_t)rD * 20 + f];
        acc.x += bf_lo(uA); acc.y += bf_hi(uA);
        acc.x += bf_lo(uB); acc.y += bf_hi(uB);
        acc.x += bf_lo(uC); acc.y += bf_hi(uC);
        acc.x += bf_lo(uD); acc.y += bf_hi(uD);
    }
    for (; j + 3 < je; j += 4) {
        int rA = pair[j + sub];
        int rB = pair[j + 2 + sub];
        unsigned uA = zb[(size_t)rA * 20 + f];
        unsigned uB = zb[(size_t)rB * 20 + f];
        acc.x += bf_lo(uA); acc.y += bf_hi(uA);
        acc.x += bf_lo(uB); acc.y += bf_hi(uB);
    }
    for (; j + 1 < je; j += 2) {
        unsigned u = zb[(size_t)pair[j + sub] * 20 + f];
        acc.x += bf_lo(u); acc.y += bf_hi(u);
    }
    if (j < je && sub == 0) {
        unsigned u = zb[(size_t)pair[j] * 20 + f];
        acc.x += bf_lo(u); acc.y += bf_hi(u);
    }

    float bx = __shfl(acc.x, sl + 32, 64);
    float by = __shfl(acc.y, sl + 32, 64);
    if (sub == 0 && sl < 20) {
        float2 bias = ((const float2*)b2)[sl];
        float2 res = make_float2((acc.x + bx) * dv + bias.x,
                                 (acc.y + by) * dv + bias.y);
        ((float2*)(out + (size_t)gw * 40))[sl] = res;
    }
}

// ---------------------------------------------------------------------------
extern "C" void kernel_launch(void* const* d_in, const int* in_sizes, int n_in,
                              void* d_out, int out_size, void* d_ws, size_t ws_size,
                              hipStream_t stream) {
    const float* x  = (const float*)d_in[0];
    const int*   ei = (const int*)d_in[1];
    const float* W1 = (const float*)d_in[2];
    const float* b1 = (const float*)d_in[3];
    const float* W2 = (const float*)d_in[4];
    const float* b2 = (const float*)d_in[5];
    float* out = (float*)d_out;

    const int N = in_sizes[0] / 128;
    const int E = in_sizes[1] / 2;
    const int* row = ei;        // sources
    const int* col = ei + E;    // targets

    const int Np = (N + 255) & ~255;
    const int nb = (N + 255) / 256;            // must be <= 512
    const int nbuck = (N + (1 << FB_SHIFT) - 1) >> FB_SHIFT;   // <= 256

    // workspace layout (4-byte units), ~92 MB total
    int*      cnt    = (int*)d_ws;                       // Np
    int*      rowptr = cnt + Np;                         // Np + 256
    int*      bsum   = rowptr + Np + 256;                // 1024
    int*      bcur   = bsum + 1024;                      // 256
    float*    dis    = (float*)(bcur + 256);             // Np
    unsigned* Wt     = (unsigned*)(dis + Np);            // 8192 (W1t bf16)
    unsigned* W2t    = Wt + 8192;                        // 3072 (W2t bf16, 48 rows)
    int*      pair   = (int*)(W2t + 3072);               // E ints (src index only)
    unsigned* xb     = (unsigned*)(pair + E);            // N*64 (bf16 x*dis)
    unsigned* xab    = xb + (size_t)N * 64;              // N*64 (bf16 A*x)
    unsigned* hb     = xab + (size_t)N * 64;             // N*64 (bf16 h)
    unsigned* zb     = hb + (size_t)N * 64;              // N*20 (bf16 z*dis)
    unsigned* bins   = (unsigned*)xab;  // alias: dead before k_gather1 writes xab

    // degree / norm / CSC build
    hipMemsetAsync(cnt, 0, (size_t)Np * sizeof(int), stream);
    k_count<<<(E + 255) / 256, 256, 0, stream>>>(col, cnt, E);
    k_scan_block<<<nb, 256, 0, stream>>>(cnt, rowptr, bsum, dis, N);
    k_scan_bsum<<<1, 512, 0, stream>>>(bsum, nb);
    k_scan_add<<<nb, 256, 0, stream>>>(rowptr, bcur, bsum, N, E);
    k_binfill<<<(E + 4095) / 4096, 256, 0, stream>>>(row, col, bcur, bins, E);
    k_fill2<<<nbuck, 256, 0, stream>>>(bins, rowptr, pair, N, E);

    // conversions (xb scaled by dis)
    k_cvt<<<(N * 64 + 255) / 256, 256, 0, stream>>>(x, dis, xb, N * 64);
    k_cvtW<<<32, 256, 0, stream>>>(W1, Wt);
    k_cvtW2<<<12, 256, 0, stream>>>(W2, W2t);

    // layer 1: xab = bf16(A x) ; hb = bf16(relu(xab @ W1 + b1))  [MFMA]
    k_gather1<<<(N + 3) / 4, 256, 0, stream>>>(xb, rowptr, pair, dis, xab, N);
    k_gemm1<<<(N + 127) / 128, 256, 0, stream>>>(xab, Wt, b1, hb, N);

    // layer 2: zb = bf16((h @ W2) * dis) [MFMA] ; out = b2 + dis*(sum zb)
    k_gemm2<<<(N + 127) / 128, 256, 0, stream>>>(hb, W2t, dis, zb, N);
    k_gather2<<<(N + 3) / 4, 256, 0, stream>>>(zb, rowptr, pair, dis, b2, out, N);
}